// Round 3
// baseline (5814.333 us; speedup 1.0000x reference)
//
#include <hip/hip_runtime.h>
#include <math.h>

// ---------------- problem constants ----------------
constexpr int BB     = 4;
constexpr int WINN   = 10;
constexpr int NNODES = 10000;
constexpr int NFEAT  = 8;
constexpr int NHID   = 64;
constexpr int NTOT   = BB * WINN * NNODES;   // 400000 stacked nodes
constexpr int NEDGE  = 3200000;
constexpr int NBN    = BB * NNODES;          // 40000 sequences
constexpr float EPSBN = 1e-5f;

#define DEVFN static __device__ __forceinline__

DEVFN float sigmoidf_(float x) { return 1.0f / (1.0f + __expf(-x)); }

// ---------------- diagnostic: report ws_size via output ----------------
__global__ void k_diag(float* out, float wsz, int n) {
    int i = blockIdx.x * 256 + threadIdx.x;
    if (i < n) out[i] = wsz;
}

// ---------------- init: deg=1 (self loop), zero LSTM states + BN sums ----------------
__global__ void k_init(float* deg, float* hA, float* cA, float* hB, float* cB, float* sums) {
    int i = blockIdx.x * 256 + threadIdx.x;   // grid covers NBN*64
    if (i < NBN * NHID) { hA[i] = 0.f; cA[i] = 0.f; hB[i] = 0.f; cB[i] = 0.f; }
    if (i < NTOT) deg[i] = 1.0f;
    if (i < 256) sums[i] = 0.f;
}

// deg[col] += ew
__global__ void k_deg(const int* __restrict__ ei, const float* __restrict__ ew, float* deg) {
    int e = blockIdx.x * 256 + threadIdx.x;
    if (e < NEDGE) atomicAdd(&deg[ei[NEDGE + e]], ew[e]);
}

__global__ void k_dinv(float* deg) {
    int i = blockIdx.x * 256 + threadIdx.x;
    if (i < NTOT) { float d = deg[i]; deg[i] = (d > 0.f) ? rsqrtf(d) : 0.f; }
}

// aggX seed: self-loop contribution dinv^2 * x  (8 channels)
__global__ void k_seed1(const float* __restrict__ x, const float* __restrict__ dinv,
                        float* __restrict__ aggX) {
    int i = blockIdx.x * 256 + threadIdx.x;   // exact grid NTOT*8/256
    int n = i >> 3;
    float dv = dinv[n];
    aggX[i] = dv * dv * x[i];
}

// layer-1 aggregation over raw features: aggX[col] += nv*x[row]; 2 threads/edge, float4
// nv computed inline: dinv[row]*ew*dinv[col]
__global__ void k_eagg8(const int* __restrict__ ei, const float* __restrict__ ew,
                        const float* __restrict__ dinv,
                        const float* __restrict__ x, float* __restrict__ aggX) {
    int i = blockIdx.x * 256 + threadIdx.x;   // exact grid NEDGE*2/256
    int e = i >> 1, q = i & 1;
    int row = ei[e], col = ei[NEDGE + e];
    float nv = dinv[row] * ew[e] * dinv[col];
    float4 v = reinterpret_cast<const float4*>(x)[row * 2 + q];
    float* dst = aggX + (size_t)col * 8 + q * 4;
    atomicAdd(dst + 0, nv * v.x);
    atomicAdd(dst + 1, nv * v.y);
    atomicAdd(dst + 2, nv * v.z);
    atomicAdd(dst + 3, nv * v.w);
}

// h1 = relu(aggX @ W1 + b) + per-channel BN stats (sum, sumsq)
__global__ void k_lin1(const float* __restrict__ aggX, const float* __restrict__ W,
                       const float* __restrict__ bias, float* __restrict__ h1,
                       float* __restrict__ sums) {
    __shared__ float sW[NFEAT * NHID];        // 512 floats
    int tid = threadIdx.x;
    sW[tid] = W[tid];
    sW[tid + 256] = W[tid + 256];
    __syncthreads();
    int c = tid & 63;                         // stride % 64 == 0 -> channel constant
    float b = bias[c];
    float s = 0.f, sq = 0.f;
    int stride = gridDim.x * 256;
    for (int i = blockIdx.x * 256 + tid; i < NTOT * 64; i += stride) {
        int n = i >> 6;
        float acc = b;
#pragma unroll
        for (int f = 0; f < NFEAT; ++f) acc += aggX[n * NFEAT + f] * sW[f * NHID + c];
        acc = acc > 0.f ? acc : 0.f;
        h1[i] = acc;
        s += acc;
        sq += acc * acc;
    }
    __shared__ float ls[4][64], lq[4][64];
    int w = tid >> 6;
    ls[w][c] = s; lq[w][c] = sq;
    __syncthreads();
    if (tid < 64) {
        atomicAdd(&sums[tid], ls[0][tid] + ls[1][tid] + ls[2][tid] + ls[3][tid]);
        atomicAdd(&sums[64 + tid], lq[0][tid] + lq[1][tid] + lq[2][tid] + lq[3][tid]);
    }
}

// per-channel scale/shift from sums
__global__ void k_bn_final(const float* __restrict__ sums, const float* __restrict__ g,
                           const float* __restrict__ b, float* __restrict__ ss) {
    int i = threadIdx.x;
    if (i >= 64) return;
    float mean = sums[i] * (1.0f / NTOT);
    float var = sums[64 + i] * (1.0f / NTOT) - mean * mean;
    float sc = g[i] * rsqrtf(var + EPSBN);
    ss[i] = sc;
    ss[64 + i] = b[i] - mean * sc;
}

// io = io*sc[c] + sh[c] in place
__global__ void k_bn_apply(float* __restrict__ io, const float* __restrict__ ss) {
    int c = threadIdx.x & 63;
    float sc = ss[c], sh = ss[64 + c];
    int stride = gridDim.x * 256;
    for (int i = blockIdx.x * 256 + threadIdx.x; i < NTOT * 64; i += stride)
        io[i] = io[i] * sc + sh;
}

// h2buf seed: dinv^2 * h1 (64 channels)
__global__ void k_seed2(const float* __restrict__ h1, const float* __restrict__ dinv,
                        float* __restrict__ h2buf) {
    int i = blockIdx.x * 256 + threadIdx.x;   // exact grid NTOT*64/256
    int n = i >> 6;
    float dv = dinv[n];
    h2buf[i] = dv * dv * h1[i];
}

// layer-2 aggregation: dst[col] += nv*src[row]; 16 threads/edge, float4 each
__global__ void k_eagg64(const int* __restrict__ ei, const float* __restrict__ ew,
                         const float* __restrict__ dinv,
                         const float* __restrict__ src, float* __restrict__ dst) {
    int i = blockIdx.x * 256 + threadIdx.x;   // exact grid NEDGE*16/256
    int e = i >> 4, q = i & 15;
    int row = ei[e], col = ei[NEDGE + e];
    float nv = dinv[row] * ew[e] * dinv[col];
    float4 v = reinterpret_cast<const float4*>(src)[row * 16 + q];
    float* d = dst + (size_t)col * 64 + q * 4;
    atomicAdd(d + 0, nv * v.x);
    atomicAdd(d + 1, nv * v.y);
    atomicAdd(d + 2, nv * v.z);
    atomicAdd(d + 3, nv * v.w);
}

// in-place: row = relu(row @ W2 + b), one wave per row, W2 column in registers; BN stats
__global__ void k_lin2(float* __restrict__ io, const float* __restrict__ W2,
                       const float* __restrict__ bias, float* __restrict__ sums) {
    int lane = threadIdx.x & 63;
    int wid = blockIdx.x * 4 + (threadIdx.x >> 6);
    int nw = gridDim.x * 4;
    float wc[64];
#pragma unroll
    for (int h = 0; h < 64; ++h) wc[h] = W2[h * 64 + lane];
    float b = bias[lane];
    float s = 0.f, sq = 0.f;
    for (int row = wid; row < NTOT; row += nw) {
        int r = __builtin_amdgcn_readfirstlane(row);
        float* hr = io + (size_t)r * 64;
        float acc = b;
#pragma unroll
        for (int h = 0; h < 64; ++h) acc += hr[h] * wc[h];
        acc = acc > 0.f ? acc : 0.f;
        hr[lane] = acc;        // safe: all lanes' loads precede the wave's store
        s += acc;
        sq += acc * acc;
    }
    atomicAdd(&sums[lane], s);
    atomicAdd(&sums[64 + lane], sq);
}

// transpose/fuse LSTM + FC1 weights
__global__ void k_prep(const float* __restrict__ wih1, const float* __restrict__ whh1,
                       const float* __restrict__ bih1, const float* __restrict__ bhh1,
                       const float* __restrict__ wih2, const float* __restrict__ whh2,
                       const float* __restrict__ bih2, const float* __restrict__ bhh2,
                       const float* __restrict__ fc1w,
                       float* wT1, float* b1, float* wT2, float* b2, float* fc1T) {
    int i = blockIdx.x * 256 + threadIdx.x;
    if (i < 192 * 256) {
        int k = i >> 8, j = i & 255;
        wT1[i] = (k < 128) ? wih1[j * 128 + k] : whh1[j * 64 + (k - 128)];
    }
    if (i < 128 * 256) {
        int k = i >> 8, j = i & 255;
        wT2[i] = (k < 64) ? wih2[j * 64 + k] : whh2[j * 64 + (k - 64)];
    }
    if (i < 208 * 64) {
        int k = i >> 6, o = i & 63;
        fc1T[i] = fc1w[o * 208 + k];
    }
    if (i < 256) { b1[i] = bih1[i] + bhh1[i]; b2[i] = bih2[i] + bhh2[i]; }
}

// One LSTM timestep. MODE 0: layer1, input=[h1[node]|h2[node]] (D1=128, node remap by t).
// MODE 1: layer2, input=inA[bn] (D1=64). Lane j owns gates (j, j+64, j+128, j+192).
template <int MODE>
__global__ void k_lstm_step(const float* __restrict__ inA, const float* __restrict__ inB,
                            float* __restrict__ h, float* __restrict__ c,
                            const float* __restrict__ wT, const float* __restrict__ bias,
                            int t) {
    constexpr int D1 = (MODE == 0) ? 128 : 64;
    constexpr int D = D1 + 64;
    constexpr int ROWS = 32;
    __shared__ __align__(16) float sin_[ROWS][D];
    int tid = threadIdx.x;
    int r0 = blockIdx.x * ROWS;

    for (int i = tid; i < ROWS * D; i += 256) {
        int r = i / D, k = i - r * D;
        int bn = r0 + r;
        float v;
        if (MODE == 0) {
            if (k < 128) {
                int b = bn / NNODES, nn = bn - b * NNODES;
                int node = (b * WINN + t) * NNODES + nn;
                v = (k < 64) ? inA[(size_t)node * 64 + k] : inB[(size_t)node * 64 + (k - 64)];
            } else {
                v = h[(size_t)bn * 64 + (k - 128)];
            }
        } else {
            v = (k < 64) ? inA[(size_t)bn * 64 + k] : h[(size_t)bn * 64 + (k - 64)];
        }
        sin_[r][k] = v;
    }
    __syncthreads();

    int lane = tid & 63, wv = tid >> 6;
    constexpr int RPW = ROWS / 4;   // 8 rows per wave
    float ai[RPW], af[RPW], ag[RPW], ao[RPW];
    float b_i = bias[lane], b_f = bias[64 + lane], b_g = bias[128 + lane], b_o = bias[192 + lane];
#pragma unroll
    for (int p = 0; p < RPW; ++p) { ai[p] = b_i; af[p] = b_f; ag[p] = b_g; ao[p] = b_o; }

    for (int k4 = 0; k4 < D / 4; ++k4) {
        float w0[4], w1[4], w2[4], w3[4];
#pragma unroll
        for (int kk = 0; kk < 4; ++kk) {
            const float* wr = wT + (k4 * 4 + kk) * 256;
            w0[kk] = wr[lane];
            w1[kk] = wr[64 + lane];
            w2[kk] = wr[128 + lane];
            w3[kk] = wr[192 + lane];
        }
#pragma unroll
        for (int p = 0; p < RPW; ++p) {
            const float4 iv = *reinterpret_cast<const float4*>(&sin_[wv * RPW + p][k4 * 4]);
            ai[p] += iv.x * w0[0] + iv.y * w0[1] + iv.z * w0[2] + iv.w * w0[3];
            af[p] += iv.x * w1[0] + iv.y * w1[1] + iv.z * w1[2] + iv.w * w1[3];
            ag[p] += iv.x * w2[0] + iv.y * w2[1] + iv.z * w2[2] + iv.w * w2[3];
            ao[p] += iv.x * w3[0] + iv.y * w3[1] + iv.z * w3[2] + iv.w * w3[3];
        }
    }

#pragma unroll
    for (int p = 0; p < RPW; ++p) {
        int row = r0 + wv * RPW + p;
        size_t idx = (size_t)row * 64 + lane;
        float ig = sigmoidf_(ai[p]);
        float fg = sigmoidf_(af[p]);
        float gg = tanhf(ag[p]);
        float og = sigmoidf_(ao[p]);
        float cv = fg * c[idx] + ig * gg;
        c[idx] = cv;
        h[idx] = og * tanhf(cv);
    }
}

// head: z = relu([hn1|hn2|skip] @ fc1^T + b1); out = relu(z @ fc2^T + b2). One wave per row.
__global__ void k_head(const float* __restrict__ hA, const float* __restrict__ hB,
                       const float* __restrict__ x, const float* __restrict__ fc1T,
                       const float* __restrict__ fc1b, const float* __restrict__ fc2w,
                       const float* __restrict__ fc2b, float* __restrict__ out) {
    int lane = threadIdx.x & 63, wv = threadIdx.x >> 6;
    int bn = blockIdx.x * 4 + wv;
    __shared__ float sz[4][208];
    int b = bn / NNODES, nn = bn - b * NNODES;
    for (int k = lane; k < 208; k += 64) {
        float v;
        if (k < 64) v = hA[(size_t)bn * 64 + k];
        else if (k < 128) v = hB[(size_t)bn * 64 + (k - 64)];
        else {
            int kk = k - 128;
            int w = kk >> 3, f = kk & 7;
            v = x[(size_t)((b * WINN + w) * NNODES + nn) * NFEAT + f];
        }
        sz[wv][k] = v;
    }
    __syncthreads();
    float acc = fc1b[lane];
    for (int k = 0; k < 208; ++k) acc += sz[wv][k] * fc1T[k * 64 + lane];
    acc = acc > 0.f ? acc : 0.f;
    float v = acc * fc2w[lane];
#pragma unroll
    for (int m = 32; m >= 1; m >>= 1) v += __shfl_xor(v, m, 64);
    if (lane == 0) {
        float z = v + fc2b[0];
        out[bn] = z > 0.f ? z : 0.f;
    }
}

// ---------------- launch ----------------
extern "C" void kernel_launch(void* const* d_in, const int* in_sizes, int n_in,
                              void* d_out, int out_size, void* d_ws, size_t ws_size,
                              hipStream_t stream) {
    const float* x     = (const float*)d_in[0];
    const int*   ei    = (const int*)d_in[1];
    const float* ew    = (const float*)d_in[2];
    const float* c1w   = (const float*)d_in[3];
    const float* c1b   = (const float*)d_in[4];
    const float* c2w   = (const float*)d_in[5];
    const float* c2b   = (const float*)d_in[6];
    const float* bn1g  = (const float*)d_in[7];
    const float* bn1b  = (const float*)d_in[8];
    const float* bn2g  = (const float*)d_in[9];
    const float* bn2b  = (const float*)d_in[10];
    const float* wih1  = (const float*)d_in[11];
    const float* whh1  = (const float*)d_in[12];
    const float* bih1  = (const float*)d_in[13];
    const float* bhh1  = (const float*)d_in[14];
    const float* wih2  = (const float*)d_in[15];
    const float* whh2  = (const float*)d_in[16];
    const float* bih2  = (const float*)d_in[17];
    const float* bhh2  = (const float*)d_in[18];
    const float* fc1w  = (const float*)d_in[19];
    const float* fc1b  = (const float*)d_in[20];
    const float* fc2w  = (const float*)d_in[21];
    const float* fc2b  = (const float*)d_in[22];
    float* out = (float*)d_out;

    float* ws = (float*)d_ws;
    size_t off = 0;
    auto A = [&](size_t n) { float* p = ws + off; off += n; return p; };
    float* dinv = A(NTOT);
    float* aggX = A((size_t)NTOT * NFEAT);   // layer-1 aggregate (8 ch)
    float* h1   = A((size_t)NTOT * 64);      // pre-BN -> h1 in place
    float* h2   = A((size_t)NTOT * 64);      // agg2 -> pre-BN -> h2 in place
    float* hA   = A((size_t)NBN * 64);
    float* cA   = A((size_t)NBN * 64);
    float* hB   = A((size_t)NBN * 64);
    float* cB   = A((size_t)NBN * 64);
    float* wT1  = A(192 * 256);
    float* wT2  = A(128 * 256);
    float* b1   = A(256);
    float* b2   = A(256);
    float* fc1T = A(208 * 64);
    float* sums = A(256);   // [sum1|sq1|sum2|sq2]
    float* ss1  = A(128);
    float* ss2  = A(128);
    // total: 65,136,256 floats = 248.5 MB (fits 256 MiB ws)

    // workspace budget check: if insufficient, report ws_size through the output
    if (ws_size < off * sizeof(float)) {
        k_diag<<<(out_size + 255) / 256, 256, 0, stream>>>(out, (float)ws_size, out_size);
        return;
    }

    // init + degree precompute
    k_init<<<NBN * 64 / 256, 256, 0, stream>>>(dinv, hA, cA, hB, cB, sums);
    k_deg<<<NEDGE / 256, 256, 0, stream>>>(ei, ew, dinv);
    k_dinv<<<(NTOT + 255) / 256, 256, 0, stream>>>(dinv);
    k_prep<<<192, 256, 0, stream>>>(wih1, whh1, bih1, bhh1, wih2, whh2, bih2, bhh2,
                                    fc1w, wT1, b1, wT2, b2, fc1T);

    // ---- GCN layer 1: aggregate raw features (8 ch), then linear+relu+stats ----
    k_seed1<<<NTOT * 8 / 256, 256, 0, stream>>>(x, dinv, aggX);
    k_eagg8<<<NEDGE * 2 / 256, 256, 0, stream>>>(ei, ew, dinv, x, aggX);
    k_lin1<<<512, 256, 0, stream>>>(aggX, c1w, c1b, h1, sums);
    k_bn_final<<<1, 64, 0, stream>>>(sums, bn1g, bn1b, ss1);
    k_bn_apply<<<2048, 256, 0, stream>>>(h1, ss1);

    // ---- GCN layer 2: aggregate h1 (64 ch), then in-place linear+relu+stats ----
    k_seed2<<<NTOT * 64 / 256, 256, 0, stream>>>(h1, dinv, h2);
    k_eagg64<<<NEDGE * 16 / 256, 256, 0, stream>>>(ei, ew, dinv, h1, h2);
    k_lin2<<<512, 256, 0, stream>>>(h2, c2w, c2b, sums + 128);
    k_bn_final<<<1, 64, 0, stream>>>(sums + 128, bn2g, bn2b, ss2);
    k_bn_apply<<<2048, 256, 0, stream>>>(h2, ss2);

    // ---- stacked LSTM, layer2 in lockstep (ys1 never materialized) ----
    for (int t = 0; t < WINN; ++t) {
        k_lstm_step<0><<<NBN / 32, 256, 0, stream>>>(h1, h2, hA, cA, wT1, b1, t);
        k_lstm_step<1><<<NBN / 32, 256, 0, stream>>>(hA, nullptr, hB, cB, wT2, b2, t);
    }

    // ---- head ----
    k_head<<<NBN / 4, 256, 0, stream>>>(hA, hB, x, fc1T, fc1b, fc2w, fc2b, out);
}

// Round 4
// 2781.805 us; speedup vs baseline: 2.0901x; 2.0901x over previous
//
#include <hip/hip_runtime.h>
#include <math.h>

// ---------------- problem constants ----------------
constexpr int BB     = 4;
constexpr int WINN   = 10;
constexpr int NNODES = 10000;
constexpr int NFEAT  = 8;
constexpr int NHID   = 64;
constexpr int NTOT   = BB * WINN * NNODES;   // 400000 stacked nodes
constexpr int NEDGE  = 3200000;
constexpr int NBN    = BB * NNODES;          // 40000 sequences
constexpr float EPSBN = 1e-5f;

#define DEVFN static __device__ __forceinline__

DEVFN float sigmoidf_(float x) { return 1.0f / (1.0f + __expf(-x)); }

// ---------------- diagnostic: report ws_size via output ----------------
__global__ void k_diag(float* out, float wsz, int n) {
    int i = blockIdx.x * 256 + threadIdx.x;
    if (i < n) out[i] = wsz;
}

// ---------------- init: deg=1 (self loop), zero hist + BN sums ----------------
__global__ void k_init(float* deg, int* cnt, float* sums) {
    int i = blockIdx.x * 256 + threadIdx.x;   // grid covers >= NTOT
    if (i < NTOT) { deg[i] = 1.0f; cnt[i] = 0; }
    if (i < 256) sums[i] = 0.f;
}

// deg[col] += ew ; cnt[col]++   (weighted degree + in-degree histogram)
__global__ void k_deg(const int* __restrict__ ei, const float* __restrict__ ew,
                      float* deg, int* cnt) {
    int e = blockIdx.x * 256 + threadIdx.x;
    if (e < NEDGE) {
        int c = ei[NEDGE + e];
        atomicAdd(&deg[c], ew[e]);
        atomicAdd(&cnt[c], 1);
    }
}

__global__ void k_dinv(float* deg) {
    int i = blockIdx.x * 256 + threadIdx.x;
    if (i < NTOT) { float d = deg[i]; deg[i] = (d > 0.f) ? rsqrtf(d) : 0.f; }
}

// ---------------- exclusive scan of cnt -> ptr (1024 elems / block) ----------------
__global__ void k_scan1(const int* __restrict__ cnt, int* __restrict__ ptr, int* __restrict__ tmp) {
    __shared__ int sdat[256];
    int tid = threadIdx.x;
    int base = blockIdx.x * 1024 + tid * 4;
    int v0 = (base + 0 < NTOT) ? cnt[base + 0] : 0;
    int v1 = (base + 1 < NTOT) ? cnt[base + 1] : 0;
    int v2 = (base + 2 < NTOT) ? cnt[base + 2] : 0;
    int v3 = (base + 3 < NTOT) ? cnt[base + 3] : 0;
    int sum = v0 + v1 + v2 + v3;
    sdat[tid] = sum;
    __syncthreads();
    for (int ofs = 1; ofs < 256; ofs <<= 1) {
        int x = (tid >= ofs) ? sdat[tid - ofs] : 0;
        __syncthreads();
        sdat[tid] += x;
        __syncthreads();
    }
    int run = sdat[tid] - sum;   // exclusive prefix of this thread's 4
    if (base + 0 < NTOT) ptr[base + 0] = run; run += v0;
    if (base + 1 < NTOT) ptr[base + 1] = run; run += v1;
    if (base + 2 < NTOT) ptr[base + 2] = run; run += v2;
    if (base + 3 < NTOT) ptr[base + 3] = run;
    if (tid == 255) tmp[blockIdx.x] = sdat[255];
}

__global__ void k_scan2(int* tmp, int nb) {
    __shared__ int st[512];
    int tid = threadIdx.x;
    int v = (tid < nb) ? tmp[tid] : 0;
    st[tid] = v;
    __syncthreads();
    for (int ofs = 1; ofs < 512; ofs <<= 1) {
        int x = (tid >= ofs) ? st[tid - ofs] : 0;
        __syncthreads();
        st[tid] += x;
        __syncthreads();
    }
    if (tid < nb) tmp[tid] = st[tid] - v;   // exclusive
}

// add block offsets; copy ptr -> cur (fill cursor); write sentinel
__global__ void k_scan3(int* __restrict__ ptr, int* __restrict__ cur, const int* __restrict__ tmp) {
    int i = blockIdx.x * 256 + threadIdx.x;
    if (i < NTOT) {
        int p = ptr[i] + tmp[i >> 10];
        ptr[i] = p;
        cur[i] = p;
    }
    if (i == 0) ptr[NTOT] = NEDGE;
}

// CSR fill: epack[pos] = (row, norm) grouped by destination col
__global__ void k_fill(const int* __restrict__ ei, const float* __restrict__ ew,
                       const float* __restrict__ dinv, int* __restrict__ cur,
                       int2* __restrict__ epack) {
    int e = blockIdx.x * 256 + threadIdx.x;
    if (e >= NEDGE) return;
    int row = ei[e], col = ei[NEDGE + e];
    float nv = dinv[row] * ew[e] * dinv[col];
    int pos = atomicAdd(&cur[col], 1);
    epack[pos] = make_int2(row, __float_as_int(nv));
}

// layer-1 gather over raw features (8 ch): one 8-lane group per node, 8 nodes/wave
__global__ void k_gather8(const int* __restrict__ ptr, const int2* __restrict__ epack,
                          const float* __restrict__ x, const float* __restrict__ dinv,
                          float* __restrict__ aggX) {
    int tid = threadIdx.x;
    int lane = tid & 63;
    int waveg = blockIdx.x * 4 + (tid >> 6);      // grid exact: NTOT/8 waves
    int g = lane >> 3, ch = lane & 7;
    int node = waveg * 8 + g;
    int beg = ptr[node], end = ptr[node + 1];
    float dv = dinv[node];
    float acc = dv * dv * x[node * 8 + ch];
    int e = beg;
    for (; e + 1 < end; e += 2) {
        int2 p0 = epack[e], p1 = epack[e + 1];
        acc += __int_as_float(p0.y) * x[p0.x * 8 + ch]
             + __int_as_float(p1.y) * x[p1.x * 8 + ch];
    }
    if (e < end) {
        int2 p = epack[e];
        acc += __int_as_float(p.y) * x[p.x * 8 + ch];
    }
    aggX[node * 8 + ch] = acc;
}

// layer-2 gather (64 ch) with self-loop seed folded in: one wave per node
__global__ void k_gather64(const int* __restrict__ ptr, const int2* __restrict__ epack,
                           const float* __restrict__ src, const float* __restrict__ dinv,
                           float* __restrict__ dst) {
    int lane = threadIdx.x & 63;
    int node = blockIdx.x * 4 + (threadIdx.x >> 6);   // grid exact: NTOT/4 blocks
    int beg = ptr[node], end = ptr[node + 1];
    float dv = dinv[node];
    float acc = dv * dv * src[(size_t)node * 64 + lane];
    int e = beg;
    for (; e + 1 < end; e += 2) {
        int2 p0 = epack[e], p1 = epack[e + 1];
        acc += __int_as_float(p0.y) * src[(size_t)p0.x * 64 + lane]
             + __int_as_float(p1.y) * src[(size_t)p1.x * 64 + lane];
    }
    if (e < end) {
        int2 p = epack[e];
        acc += __int_as_float(p.y) * src[(size_t)p.x * 64 + lane];
    }
    dst[(size_t)node * 64 + lane] = acc;
}

// h1 = relu(aggX @ W1 + b) + per-channel BN stats (sum, sumsq)
__global__ void k_lin1(const float* __restrict__ aggX, const float* __restrict__ W,
                       const float* __restrict__ bias, float* __restrict__ h1,
                       float* __restrict__ sums) {
    __shared__ float sW[NFEAT * NHID];        // 512 floats
    int tid = threadIdx.x;
    sW[tid] = W[tid];
    sW[tid + 256] = W[tid + 256];
    __syncthreads();
    int c = tid & 63;                         // stride % 64 == 0 -> channel constant
    float b = bias[c];
    float s = 0.f, sq = 0.f;
    int stride = gridDim.x * 256;
    for (int i = blockIdx.x * 256 + tid; i < NTOT * 64; i += stride) {
        int n = i >> 6;
        float acc = b;
#pragma unroll
        for (int f = 0; f < NFEAT; ++f) acc += aggX[n * NFEAT + f] * sW[f * NHID + c];
        acc = acc > 0.f ? acc : 0.f;
        h1[i] = acc;
        s += acc;
        sq += acc * acc;
    }
    __shared__ float ls[4][64], lq[4][64];
    int w = tid >> 6;
    ls[w][c] = s; lq[w][c] = sq;
    __syncthreads();
    if (tid < 64) {
        atomicAdd(&sums[tid], ls[0][tid] + ls[1][tid] + ls[2][tid] + ls[3][tid]);
        atomicAdd(&sums[64 + tid], lq[0][tid] + lq[1][tid] + lq[2][tid] + lq[3][tid]);
    }
}

// per-channel scale/shift from sums
__global__ void k_bn_final(const float* __restrict__ sums, const float* __restrict__ g,
                           const float* __restrict__ b, float* __restrict__ ss) {
    int i = threadIdx.x;
    if (i >= 64) return;
    float mean = sums[i] * (1.0f / NTOT);
    float var = sums[64 + i] * (1.0f / NTOT) - mean * mean;
    float sc = g[i] * rsqrtf(var + EPSBN);
    ss[i] = sc;
    ss[64 + i] = b[i] - mean * sc;
}

// io = io*sc[c] + sh[c] in place
__global__ void k_bn_apply(float* __restrict__ io, const float* __restrict__ ss) {
    int c = threadIdx.x & 63;
    float sc = ss[c], sh = ss[64 + c];
    int stride = gridDim.x * 256;
    for (int i = blockIdx.x * 256 + threadIdx.x; i < NTOT * 64; i += stride)
        io[i] = io[i] * sc + sh;
}

// in-place: row = relu(row @ W2 + b), one wave per row, W2 column in registers; BN stats
__global__ void k_lin2(float* __restrict__ io, const float* __restrict__ W2,
                       const float* __restrict__ bias, float* __restrict__ sums) {
    int lane = threadIdx.x & 63;
    int wid = blockIdx.x * 4 + (threadIdx.x >> 6);
    int nw = gridDim.x * 4;
    float wc[64];
#pragma unroll
    for (int h = 0; h < 64; ++h) wc[h] = W2[h * 64 + lane];
    float b = bias[lane];
    float s = 0.f, sq = 0.f;
    for (int row = wid; row < NTOT; row += nw) {
        int r = __builtin_amdgcn_readfirstlane(row);
        float* hr = io + (size_t)r * 64;
        float acc = b;
#pragma unroll
        for (int h = 0; h < 64; ++h) acc += hr[h] * wc[h];
        acc = acc > 0.f ? acc : 0.f;
        hr[lane] = acc;        // safe: all lanes' loads precede the wave's store
        s += acc;
        sq += acc * acc;
    }
    atomicAdd(&sums[lane], s);
    atomicAdd(&sums[64 + lane], sq);
}

// zero LSTM states (after CSR region is dead)
__global__ void k_zero4(float* hA, float* cA, float* hB, float* cB) {
    int i = blockIdx.x * 256 + threadIdx.x;   // grid exact NBN*64/256
    hA[i] = 0.f; cA[i] = 0.f; hB[i] = 0.f; cB[i] = 0.f;
}

// transpose/fuse LSTM + FC1 weights
__global__ void k_prep(const float* __restrict__ wih1, const float* __restrict__ whh1,
                       const float* __restrict__ bih1, const float* __restrict__ bhh1,
                       const float* __restrict__ wih2, const float* __restrict__ whh2,
                       const float* __restrict__ bih2, const float* __restrict__ bhh2,
                       const float* __restrict__ fc1w,
                       float* wT1, float* b1, float* wT2, float* b2, float* fc1T) {
    int i = blockIdx.x * 256 + threadIdx.x;
    if (i < 192 * 256) {
        int k = i >> 8, j = i & 255;
        wT1[i] = (k < 128) ? wih1[j * 128 + k] : whh1[j * 64 + (k - 128)];
    }
    if (i < 128 * 256) {
        int k = i >> 8, j = i & 255;
        wT2[i] = (k < 64) ? wih2[j * 64 + k] : whh2[j * 64 + (k - 64)];
    }
    if (i < 208 * 64) {
        int k = i >> 6, o = i & 63;
        fc1T[i] = fc1w[o * 208 + k];
    }
    if (i < 256) { b1[i] = bih1[i] + bhh1[i]; b2[i] = bih2[i] + bhh2[i]; }
}

// One LSTM timestep. MODE 0: layer1, input=[h1[node]|h2[node]] (D1=128, node remap by t).
// MODE 1: layer2, input=inA[bn] (D1=64). Lane j owns gates (j, j+64, j+128, j+192).
template <int MODE>
__global__ void k_lstm_step(const float* __restrict__ inA, const float* __restrict__ inB,
                            float* __restrict__ h, float* __restrict__ c,
                            const float* __restrict__ wT, const float* __restrict__ bias,
                            int t) {
    constexpr int D1 = (MODE == 0) ? 128 : 64;
    constexpr int D = D1 + 64;
    constexpr int ROWS = 32;
    __shared__ __align__(16) float sin_[ROWS][D];
    int tid = threadIdx.x;
    int r0 = blockIdx.x * ROWS;

    for (int i = tid; i < ROWS * D; i += 256) {
        int r = i / D, k = i - r * D;
        int bn = r0 + r;
        float v;
        if (MODE == 0) {
            if (k < 128) {
                int b = bn / NNODES, nn = bn - b * NNODES;
                int node = (b * WINN + t) * NNODES + nn;
                v = (k < 64) ? inA[(size_t)node * 64 + k] : inB[(size_t)node * 64 + (k - 64)];
            } else {
                v = h[(size_t)bn * 64 + (k - 128)];
            }
        } else {
            v = (k < 64) ? inA[(size_t)bn * 64 + k] : h[(size_t)bn * 64 + (k - 64)];
        }
        sin_[r][k] = v;
    }
    __syncthreads();

    int lane = tid & 63, wv = tid >> 6;
    constexpr int RPW = ROWS / 4;   // 8 rows per wave
    float ai[RPW], af[RPW], ag[RPW], ao[RPW];
    float b_i = bias[lane], b_f = bias[64 + lane], b_g = bias[128 + lane], b_o = bias[192 + lane];
#pragma unroll
    for (int p = 0; p < RPW; ++p) { ai[p] = b_i; af[p] = b_f; ag[p] = b_g; ao[p] = b_o; }

    for (int k4 = 0; k4 < D / 4; ++k4) {
        float w0[4], w1[4], w2[4], w3[4];
#pragma unroll
        for (int kk = 0; kk < 4; ++kk) {
            const float* wr = wT + (k4 * 4 + kk) * 256;
            w0[kk] = wr[lane];
            w1[kk] = wr[64 + lane];
            w2[kk] = wr[128 + lane];
            w3[kk] = wr[192 + lane];
        }
#pragma unroll
        for (int p = 0; p < RPW; ++p) {
            const float4 iv = *reinterpret_cast<const float4*>(&sin_[wv * RPW + p][k4 * 4]);
            ai[p] += iv.x * w0[0] + iv.y * w0[1] + iv.z * w0[2] + iv.w * w0[3];
            af[p] += iv.x * w1[0] + iv.y * w1[1] + iv.z * w1[2] + iv.w * w1[3];
            ag[p] += iv.x * w2[0] + iv.y * w2[1] + iv.z * w2[2] + iv.w * w2[3];
            ao[p] += iv.x * w3[0] + iv.y * w3[1] + iv.z * w3[2] + iv.w * w3[3];
        }
    }

#pragma unroll
    for (int p = 0; p < RPW; ++p) {
        int row = r0 + wv * RPW + p;
        size_t idx = (size_t)row * 64 + lane;
        float ig = sigmoidf_(ai[p]);
        float fg = sigmoidf_(af[p]);
        float gg = tanhf(ag[p]);
        float og = sigmoidf_(ao[p]);
        float cv = fg * c[idx] + ig * gg;
        c[idx] = cv;
        h[idx] = og * tanhf(cv);
    }
}

// head: z = relu([hn1|hn2|skip] @ fc1^T + b1); out = relu(z @ fc2^T + b2). One wave per row.
__global__ void k_head(const float* __restrict__ hA, const float* __restrict__ hB,
                       const float* __restrict__ x, const float* __restrict__ fc1T,
                       const float* __restrict__ fc1b, const float* __restrict__ fc2w,
                       const float* __restrict__ fc2b, float* __restrict__ out) {
    int lane = threadIdx.x & 63, wv = threadIdx.x >> 6;
    int bn = blockIdx.x * 4 + wv;
    __shared__ float sz[4][208];
    int b = bn / NNODES, nn = bn - b * NNODES;
    for (int k = lane; k < 208; k += 64) {
        float v;
        if (k < 64) v = hA[(size_t)bn * 64 + k];
        else if (k < 128) v = hB[(size_t)bn * 64 + (k - 64)];
        else {
            int kk = k - 128;
            int w = kk >> 3, f = kk & 7;
            v = x[(size_t)((b * WINN + w) * NNODES + nn) * NFEAT + f];
        }
        sz[wv][k] = v;
    }
    __syncthreads();
    float acc = fc1b[lane];
    for (int k = 0; k < 208; ++k) acc += sz[wv][k] * fc1T[k * 64 + lane];
    acc = acc > 0.f ? acc : 0.f;
    float v = acc * fc2w[lane];
#pragma unroll
    for (int m = 32; m >= 1; m >>= 1) v += __shfl_xor(v, m, 64);
    if (lane == 0) {
        float z = v + fc2b[0];
        out[bn] = z > 0.f ? z : 0.f;
    }
}

// ---------------- launch ----------------
extern "C" void kernel_launch(void* const* d_in, const int* in_sizes, int n_in,
                              void* d_out, int out_size, void* d_ws, size_t ws_size,
                              hipStream_t stream) {
    const float* x     = (const float*)d_in[0];
    const int*   ei    = (const int*)d_in[1];
    const float* ew    = (const float*)d_in[2];
    const float* c1w   = (const float*)d_in[3];
    const float* c1b   = (const float*)d_in[4];
    const float* c2w   = (const float*)d_in[5];
    const float* c2b   = (const float*)d_in[6];
    const float* bn1g  = (const float*)d_in[7];
    const float* bn1b  = (const float*)d_in[8];
    const float* bn2g  = (const float*)d_in[9];
    const float* bn2b  = (const float*)d_in[10];
    const float* wih1  = (const float*)d_in[11];
    const float* whh1  = (const float*)d_in[12];
    const float* bih1  = (const float*)d_in[13];
    const float* bhh1  = (const float*)d_in[14];
    const float* wih2  = (const float*)d_in[15];
    const float* whh2  = (const float*)d_in[16];
    const float* bih2  = (const float*)d_in[17];
    const float* bhh2  = (const float*)d_in[18];
    const float* fc1w  = (const float*)d_in[19];
    const float* fc1b  = (const float*)d_in[20];
    const float* fc2w  = (const float*)d_in[21];
    const float* fc2b  = (const float*)d_in[22];
    float* out = (float*)d_out;

    float* ws = (float*)d_ws;
    size_t off = 0;
    auto A = [&](size_t n) { float* p = ws + off; off += n; return p; };
    float* dinv = A(NTOT);
    float* aggX = A((size_t)NTOT * NFEAT);   // layer-1 aggregate (8 ch)
    float* h1   = A((size_t)NTOT * 64);      // pre-BN -> h1 in place
    float* h2   = A((size_t)NTOT * 64);      // agg2 -> pre-BN -> h2 in place

    // ---- union region: CSR (GCN phase) aliases LSTM state (LSTM phase) ----
    size_t uoff = off;
    float* hA   = A((size_t)NBN * 64);
    float* cA   = A((size_t)NBN * 64);
    float* hB   = A((size_t)NBN * 64);
    float* cB   = A((size_t)NBN * 64);
    int2* epack = (int2*)(ws + uoff);                 // NEDGE int2 (8B-aligned: uoff*4 % 8 == 0)
    int*  ptr   = (int*)(epack + NEDGE);              // NTOT+1
    int*  cur   = ptr + NTOT + 1;                     // NTOT (hist, then fill cursor)
    // CSR total = 2*NEDGE + 2*NTOT + 1 ints = 7.2M < 10.24M floats of LSTM state ✓

    float* wT1  = A(192 * 256);
    float* wT2  = A(128 * 256);
    float* b1   = A(256);
    float* b2   = A(256);
    float* fc1T = A(208 * 64);
    float* sums = A(256);   // [sum1|sq1|sum2|sq2]
    float* ss1  = A(128);
    float* ss2  = A(128);
    float* scanTmpF = A(512);
    int* scanTmp = (int*)scanTmpF;
    // total ~65.1M floats = 260.5 MB <= 256 MiB ws

    // workspace budget check: if insufficient, report ws_size through the output
    if (ws_size < off * sizeof(float)) {
        k_diag<<<(out_size + 255) / 256, 256, 0, stream>>>(out, (float)ws_size, out_size);
        return;
    }

    constexpr int SCAN_NB = (NTOT + 1023) / 1024;   // 391

    // init + degree + CSR build
    k_init<<<(NTOT + 255) / 256, 256, 0, stream>>>(dinv, cur, sums);
    k_deg<<<NEDGE / 256, 256, 0, stream>>>(ei, ew, dinv, cur);
    k_dinv<<<(NTOT + 255) / 256, 256, 0, stream>>>(dinv);
    k_scan1<<<SCAN_NB, 256, 0, stream>>>(cur, ptr, scanTmp);
    k_scan2<<<1, 512, 0, stream>>>(scanTmp, SCAN_NB);
    k_scan3<<<(NTOT + 255) / 256, 256, 0, stream>>>(ptr, cur, scanTmp);
    k_fill<<<NEDGE / 256, 256, 0, stream>>>(ei, ew, dinv, cur, epack);
    k_prep<<<192, 256, 0, stream>>>(wih1, whh1, bih1, bhh1, wih2, whh2, bih2, bhh2,
                                    fc1w, wT1, b1, wT2, b2, fc1T);

    // ---- GCN layer 1: gather raw features (8 ch), then linear+relu+stats ----
    k_gather8<<<NTOT / 8 / 4, 256, 0, stream>>>(ptr, epack, x, dinv, aggX);
    k_lin1<<<512, 256, 0, stream>>>(aggX, c1w, c1b, h1, sums);
    k_bn_final<<<1, 64, 0, stream>>>(sums, bn1g, bn1b, ss1);
    k_bn_apply<<<2048, 256, 0, stream>>>(h1, ss1);

    // ---- GCN layer 2: gather h1 (64 ch, seed folded), then in-place linear+relu+stats ----
    k_gather64<<<NTOT / 4, 256, 0, stream>>>(ptr, epack, h1, dinv, h2);
    k_lin2<<<512, 256, 0, stream>>>(h2, c2w, c2b, sums + 128);
    k_bn_final<<<1, 64, 0, stream>>>(sums + 128, bn2g, bn2b, ss2);
    k_bn_apply<<<2048, 256, 0, stream>>>(h2, ss2);

    // ---- LSTM states (CSR region now dead) ----
    k_zero4<<<NBN * 64 / 256, 256, 0, stream>>>(hA, cA, hB, cB);

    // ---- stacked LSTM, layer2 in lockstep (ys1 never materialized) ----
    for (int t = 0; t < WINN; ++t) {
        k_lstm_step<0><<<NBN / 32, 256, 0, stream>>>(h1, h2, hA, cA, wT1, b1, t);
        k_lstm_step<1><<<NBN / 32, 256, 0, stream>>>(hA, nullptr, hB, cB, wT2, b2, t);
    }

    // ---- head ----
    k_head<<<NBN / 4, 256, 0, stream>>>(hA, hB, x, fc1T, fc1b, fc2w, fc2b, out);
}

// Round 5
// 2664.670 us; speedup vs baseline: 2.1820x; 1.0440x over previous
//
#include <hip/hip_runtime.h>
#include <math.h>

// ---------------- problem constants ----------------
constexpr int BB     = 4;
constexpr int WINN   = 10;
constexpr int NNODES = 10000;
constexpr int NFEAT  = 8;
constexpr int NHID   = 64;
constexpr int NTOT   = BB * WINN * NNODES;   // 400000 stacked nodes
constexpr int NEDGE  = 3200000;
constexpr int NBN    = BB * NNODES;          // 40000 sequences
constexpr float EPSBN = 1e-5f;

#define DEVFN static __device__ __forceinline__

DEVFN float sigmoidf_(float x) { return 1.0f / (1.0f + __expf(-x)); }
// tanh(x) = 2*sigmoid(2x) - 1  (no inf/inf NaN; saturates correctly)
DEVFN float tanhf_(float x) { return 2.0f / (1.0f + __expf(-2.0f * x)) - 1.0f; }

// ---------------- diagnostic: report ws_size via output ----------------
__global__ void k_diag(float* out, float wsz, int n) {
    int i = blockIdx.x * 256 + threadIdx.x;
    if (i < n) out[i] = wsz;
}

// ---------------- init: deg=1 (self loop), zero hist + BN sums ----------------
__global__ void k_init(float* deg, int* cnt, float* sums) {
    int i = blockIdx.x * 256 + threadIdx.x;   // grid covers >= NTOT
    if (i < NTOT) { deg[i] = 1.0f; cnt[i] = 0; }
    if (i < 2048) sums[i] = 0.f;
}

// deg[col] += ew ; cnt[col]++   (weighted degree + in-degree histogram)
__global__ void k_deg(const int* __restrict__ ei, const float* __restrict__ ew,
                      float* deg, int* cnt) {
    int e = blockIdx.x * 256 + threadIdx.x;
    if (e < NEDGE) {
        int c = ei[NEDGE + e];
        atomicAdd(&deg[c], ew[e]);
        atomicAdd(&cnt[c], 1);
    }
}

__global__ void k_dinv(float* deg) {
    int i = blockIdx.x * 256 + threadIdx.x;
    if (i < NTOT) { float d = deg[i]; deg[i] = (d > 0.f) ? rsqrtf(d) : 0.f; }
}

// ---------------- exclusive scan of cnt -> ptr (1024 elems / block) ----------------
__global__ void k_scan1(const int* __restrict__ cnt, int* __restrict__ ptr, int* __restrict__ tmp) {
    __shared__ int sdat[256];
    int tid = threadIdx.x;
    int base = blockIdx.x * 1024 + tid * 4;
    int v0 = (base + 0 < NTOT) ? cnt[base + 0] : 0;
    int v1 = (base + 1 < NTOT) ? cnt[base + 1] : 0;
    int v2 = (base + 2 < NTOT) ? cnt[base + 2] : 0;
    int v3 = (base + 3 < NTOT) ? cnt[base + 3] : 0;
    int sum = v0 + v1 + v2 + v3;
    sdat[tid] = sum;
    __syncthreads();
    for (int ofs = 1; ofs < 256; ofs <<= 1) {
        int x = (tid >= ofs) ? sdat[tid - ofs] : 0;
        __syncthreads();
        sdat[tid] += x;
        __syncthreads();
    }
    int run = sdat[tid] - sum;   // exclusive prefix of this thread's 4
    if (base + 0 < NTOT) ptr[base + 0] = run; run += v0;
    if (base + 1 < NTOT) ptr[base + 1] = run; run += v1;
    if (base + 2 < NTOT) ptr[base + 2] = run; run += v2;
    if (base + 3 < NTOT) ptr[base + 3] = run;
    if (tid == 255) tmp[blockIdx.x] = sdat[255];
}

__global__ void k_scan2(int* tmp, int nb) {
    __shared__ int st[512];
    int tid = threadIdx.x;
    int v = (tid < nb) ? tmp[tid] : 0;
    st[tid] = v;
    __syncthreads();
    for (int ofs = 1; ofs < 512; ofs <<= 1) {
        int x = (tid >= ofs) ? st[tid - ofs] : 0;
        __syncthreads();
        st[tid] += x;
        __syncthreads();
    }
    if (tid < nb) tmp[tid] = st[tid] - v;   // exclusive
}

// add block offsets; copy ptr -> cur (fill cursor); write sentinel
__global__ void k_scan3(int* __restrict__ ptr, int* __restrict__ cur, const int* __restrict__ tmp) {
    int i = blockIdx.x * 256 + threadIdx.x;
    if (i < NTOT) {
        int p = ptr[i] + tmp[i >> 10];
        ptr[i] = p;
        cur[i] = p;
    }
    if (i == 0) ptr[NTOT] = NEDGE;
}

// CSR fill: epack[pos] = (row, norm) grouped by destination col
__global__ void k_fill(const int* __restrict__ ei, const float* __restrict__ ew,
                       const float* __restrict__ dinv, int* __restrict__ cur,
                       int2* __restrict__ epack) {
    int e = blockIdx.x * 256 + threadIdx.x;
    if (e >= NEDGE) return;
    int row = ei[e], col = ei[NEDGE + e];
    float nv = dinv[row] * ew[e] * dinv[col];
    int pos = atomicAdd(&cur[col], 1);
    epack[pos] = make_int2(row, __float_as_int(nv));
}

// layer-1 gather over raw features (8 ch): one 8-lane group per node, 8 nodes/wave
__global__ void k_gather8(const int* __restrict__ ptr, const int2* __restrict__ epack,
                          const float* __restrict__ x, const float* __restrict__ dinv,
                          float* __restrict__ aggX) {
    int tid = threadIdx.x;
    int lane = tid & 63;
    int waveg = blockIdx.x * 4 + (tid >> 6);      // grid exact: NTOT/8 waves
    int g = lane >> 3, ch = lane & 7;
    int node = waveg * 8 + g;
    int beg = ptr[node], end = ptr[node + 1];
    float dv = dinv[node];
    float acc = dv * dv * x[node * 8 + ch];
    int e = beg;
    for (; e + 1 < end; e += 2) {
        int2 p0 = epack[e], p1 = epack[e + 1];
        acc += __int_as_float(p0.y) * x[p0.x * 8 + ch]
             + __int_as_float(p1.y) * x[p1.x * 8 + ch];
    }
    if (e < end) {
        int2 p = epack[e];
        acc += __int_as_float(p.y) * x[p.x * 8 + ch];
    }
    aggX[node * 8 + ch] = acc;
}

// layer-2 gather (64 ch) with self-loop seed folded in: one wave per node
__global__ void k_gather64(const int* __restrict__ ptr, const int2* __restrict__ epack,
                           const float* __restrict__ src, const float* __restrict__ dinv,
                           float* __restrict__ dst) {
    int lane = threadIdx.x & 63;
    int node = blockIdx.x * 4 + (threadIdx.x >> 6);   // grid exact: NTOT/4 blocks
    int beg = ptr[node], end = ptr[node + 1];
    float dv = dinv[node];
    float acc = dv * dv * src[(size_t)node * 64 + lane];
    int e = beg;
    for (; e + 1 < end; e += 2) {
        int2 p0 = epack[e], p1 = epack[e + 1];
        acc += __int_as_float(p0.y) * src[(size_t)p0.x * 64 + lane]
             + __int_as_float(p1.y) * src[(size_t)p1.x * 64 + lane];
    }
    if (e < end) {
        int2 p = epack[e];
        acc += __int_as_float(p.y) * src[(size_t)p.x * 64 + lane];
    }
    dst[(size_t)node * 64 + lane] = acc;
}

// h1 = relu(aggX @ W1 + b) + per-channel BN stats (sum, sumsq)
__global__ void k_lin1(const float* __restrict__ aggX, const float* __restrict__ W,
                       const float* __restrict__ bias, float* __restrict__ h1,
                       float* __restrict__ sums) {
    __shared__ float sW[NFEAT * NHID];        // 512 floats
    int tid = threadIdx.x;
    sW[tid] = W[tid];
    sW[tid + 256] = W[tid + 256];
    __syncthreads();
    int c = tid & 63;                         // stride % 64 == 0 -> channel constant
    float b = bias[c];
    float s = 0.f, sq = 0.f;
    int stride = gridDim.x * 256;
    for (int i = blockIdx.x * 256 + tid; i < NTOT * 64; i += stride) {
        int n = i >> 6;
        float acc = b;
#pragma unroll
        for (int f = 0; f < NFEAT; ++f) acc += aggX[n * NFEAT + f] * sW[f * NHID + c];
        acc = acc > 0.f ? acc : 0.f;
        h1[i] = acc;
        s += acc;
        sq += acc * acc;
    }
    __shared__ float ls[4][64], lq[4][64];
    int w = tid >> 6;
    ls[w][c] = s; lq[w][c] = sq;
    __syncthreads();
    if (tid < 64) {
        atomicAdd(&sums[tid], ls[0][tid] + ls[1][tid] + ls[2][tid] + ls[3][tid]);
        atomicAdd(&sums[64 + tid], lq[0][tid] + lq[1][tid] + lq[2][tid] + lq[3][tid]);
    }
}

// per-channel scale/shift from sums (single accumulator copy)
__global__ void k_bn_final(const float* __restrict__ sums, const float* __restrict__ g,
                           const float* __restrict__ b, float* __restrict__ ss) {
    int i = threadIdx.x;
    if (i >= 64) return;
    float mean = sums[i] * (1.0f / NTOT);
    float var = sums[64 + i] * (1.0f / NTOT) - mean * mean;
    float sc = g[i] * rsqrtf(var + EPSBN);
    ss[i] = sc;
    ss[64 + i] = b[i] - mean * sc;
}

// per-channel scale/shift from 8 spread accumulator copies
__global__ void k_bn_final8(const float* __restrict__ sums8, const float* __restrict__ g,
                            const float* __restrict__ b, float* __restrict__ ss) {
    int i = threadIdx.x;
    if (i >= 64) return;
    float S = 0.f, Q = 0.f;
#pragma unroll
    for (int m = 0; m < 8; ++m) { S += sums8[m * 128 + i]; Q += sums8[m * 128 + 64 + i]; }
    float mean = S * (1.0f / NTOT);
    float var = Q * (1.0f / NTOT) - mean * mean;
    float sc = g[i] * rsqrtf(var + EPSBN);
    ss[i] = sc;
    ss[64 + i] = b[i] - mean * sc;
}

// io = io*sc[c] + sh[c] in place
__global__ void k_bn_apply(float* __restrict__ io, const float* __restrict__ ss) {
    int c = threadIdx.x & 63;
    float sc = ss[c], sh = ss[64 + c];
    int stride = gridDim.x * 256;
    for (int i = blockIdx.x * 256 + threadIdx.x; i < NTOT * 64; i += stride)
        io[i] = io[i] * sc + sh;
}

// in-place row = relu(row @ W2 + b): LDS-staged broadcast (no scalar-load chain)
__global__ void k_lin2b(float* __restrict__ io, const float* __restrict__ W2,
                        const float* __restrict__ bias, float* __restrict__ sums8) {
    __shared__ __align__(16) float srow[4][64];
    __shared__ float ls[4][64], lq[4][64];
    int lane = threadIdx.x & 63, wv = threadIdx.x >> 6;
    float wc[64];
#pragma unroll
    for (int h = 0; h < 64; ++h) wc[h] = W2[h * 64 + lane];
    float b = bias[lane];
    float s = 0.f, sq = 0.f;
    int wid = blockIdx.x * 4 + wv;
    int nw = gridDim.x * 4;
    for (int row = wid; row < NTOT; row += nw) {
        float* hr = io + (size_t)row * 64;
        srow[wv][lane] = hr[lane];            // coalesced 256B load -> LDS
        float acc = b;
#pragma unroll
        for (int h4 = 0; h4 < 16; ++h4) {     // broadcast float4 reads
            float4 iv = *reinterpret_cast<const float4*>(&srow[wv][h4 * 4]);
            acc += iv.x * wc[h4 * 4] + iv.y * wc[h4 * 4 + 1]
                 + iv.z * wc[h4 * 4 + 2] + iv.w * wc[h4 * 4 + 3];
        }
        acc = acc > 0.f ? acc : 0.f;
        hr[lane] = acc;
        s += acc;
        sq += acc * acc;
    }
    ls[wv][lane] = s; lq[wv][lane] = sq;
    __syncthreads();
    if (threadIdx.x < 64) {
        float S = ls[0][lane] + ls[1][lane] + ls[2][lane] + ls[3][lane];
        float Q = lq[0][lane] + lq[1][lane] + lq[2][lane] + lq[3][lane];
        float* dst = sums8 + (blockIdx.x & 7) * 128;
        atomicAdd(&dst[lane], S);
        atomicAdd(&dst[64 + lane], Q);
    }
}

// transpose/fuse LSTM + FC1 weights
__global__ void k_prep(const float* __restrict__ wih1, const float* __restrict__ whh1,
                       const float* __restrict__ bih1, const float* __restrict__ bhh1,
                       const float* __restrict__ wih2, const float* __restrict__ whh2,
                       const float* __restrict__ bih2, const float* __restrict__ bhh2,
                       const float* __restrict__ fc1w,
                       float* wT1, float* b1, float* wT2, float* b2, float* fc1T) {
    int i = blockIdx.x * 256 + threadIdx.x;
    if (i < 192 * 256) {
        int k = i >> 8, j = i & 255;
        wT1[i] = (k < 128) ? wih1[j * 128 + k] : whh1[j * 64 + (k - 128)];
    }
    if (i < 128 * 256) {
        int k = i >> 8, j = i & 255;
        wT2[i] = (k < 64) ? wih2[j * 64 + k] : whh2[j * 64 + (k - 64)];
    }
    if (i < 208 * 64) {
        int k = i >> 6, o = i & 63;
        fc1T[i] = fc1w[o * 208 + k];
    }
    if (i < 256) { b1[i] = bih1[i] + bhh1[i]; b2[i] = bih2[i] + bhh2[i]; }
}

// ---------------- persistent fused 2-layer LSTM, all 10 timesteps ----------------
// Block = 4 waves, 64 rows; wave owns 16 rows for the whole sequence.
// States h/c (both layers) live in registers; per-t inputs staged in LDS.
// Lane j owns hidden unit j (gates j, j+64, j+128, j+192).
__global__ __launch_bounds__(256) void k_lstm_all(
    const float* __restrict__ h1, const float* __restrict__ h2,
    const float* __restrict__ wT1, const float* __restrict__ wT2,
    const float* __restrict__ bs1, const float* __restrict__ bs2,
    float* __restrict__ hA, float* __restrict__ hB) {
    constexpr int RPW = 16;
    __shared__ __align__(16) float sin_[64][192];   // 48 KB
    int tid = threadIdx.x;
    int lane = tid & 63, wv = tid >> 6;
    int lrow = wv * RPW;                      // wave's LDS row base
    int rbase = blockIdx.x * 64 + lrow;       // wave's first global row (bn)

    float hA_r[RPW], cA_r[RPW], hB_r[RPW], cB_r[RPW];
#pragma unroll
    for (int p = 0; p < RPW; ++p) { hA_r[p] = 0.f; cA_r[p] = 0.f; hB_r[p] = 0.f; cB_r[p] = 0.f; }

    float b1i = bs1[lane], b1f = bs1[64 + lane], b1g = bs1[128 + lane], b1o = bs1[192 + lane];
    float b2i = bs2[lane], b2f = bs2[64 + lane], b2g = bs2[128 + lane], b2o = bs2[192 + lane];

    for (int t = 0; t < WINN; ++t) {
        // ---- stage layer-1 input [h1(node)|h2(node)] into cols 0..127 (wave-local rows)
#pragma unroll
        for (int it = 0; it < 8; ++it) {
            int idx = it * 64 + lane;         // 0..511 = 16 rows * 32 float4
            int r = idx >> 5, f = idx & 31;
            int bn = rbase + r;
            int b = bn / NNODES, nn = bn - b * NNODES;
            size_t node = (size_t)((b * WINN + t) * NNODES + nn);
            float4 v = (f < 16) ? reinterpret_cast<const float4*>(h1)[node * 16 + f]
                                : reinterpret_cast<const float4*>(h2)[node * 16 + (f - 16)];
            *reinterpret_cast<float4*>(&sin_[lrow + r][f * 4]) = v;
        }
        // own h_layer1 -> cols 128..191
#pragma unroll
        for (int p = 0; p < RPW; ++p) sin_[lrow + p][128 + lane] = hA_r[p];

        // ---- layer-1 gates (K = 192)
        float ai[RPW], af[RPW], ag[RPW], ao[RPW];
#pragma unroll
        for (int p = 0; p < RPW; ++p) { ai[p] = b1i; af[p] = b1f; ag[p] = b1g; ao[p] = b1o; }
        for (int k4 = 0; k4 < 48; ++k4) {
            float w0[4], w1[4], w2[4], w3[4];
#pragma unroll
            for (int kk = 0; kk < 4; ++kk) {
                const float* wr = wT1 + (k4 * 4 + kk) * 256;
                w0[kk] = wr[lane]; w1[kk] = wr[64 + lane];
                w2[kk] = wr[128 + lane]; w3[kk] = wr[192 + lane];
            }
#pragma unroll
            for (int p = 0; p < RPW; ++p) {
                const float4 iv = *reinterpret_cast<const float4*>(&sin_[lrow + p][k4 * 4]);
                ai[p] += iv.x * w0[0] + iv.y * w0[1] + iv.z * w0[2] + iv.w * w0[3];
                af[p] += iv.x * w1[0] + iv.y * w1[1] + iv.z * w1[2] + iv.w * w1[3];
                ag[p] += iv.x * w2[0] + iv.y * w2[1] + iv.z * w2[2] + iv.w * w2[3];
                ao[p] += iv.x * w3[0] + iv.y * w3[1] + iv.z * w3[2] + iv.w * w3[3];
            }
        }
        // ---- layer-1 update; stage layer-2 input [h_l1|hB] into cols 0..127
#pragma unroll
        for (int p = 0; p < RPW; ++p) {
            float ig = sigmoidf_(ai[p]);
            float fg = sigmoidf_(af[p]);
            float gg = tanhf_(ag[p]);
            float og = sigmoidf_(ao[p]);
            float cv = fg * cA_r[p] + ig * gg;
            cA_r[p] = cv;
            float hv = og * tanhf_(cv);
            hA_r[p] = hv;
            sin_[lrow + p][lane] = hv;
            sin_[lrow + p][64 + lane] = hB_r[p];
        }
        // ---- layer-2 gates (K = 128)
#pragma unroll
        for (int p = 0; p < RPW; ++p) { ai[p] = b2i; af[p] = b2f; ag[p] = b2g; ao[p] = b2o; }
        for (int k4 = 0; k4 < 32; ++k4) {
            float w0[4], w1[4], w2[4], w3[4];
#pragma unroll
            for (int kk = 0; kk < 4; ++kk) {
                const float* wr = wT2 + (k4 * 4 + kk) * 256;
                w0[kk] = wr[lane]; w1[kk] = wr[64 + lane];
                w2[kk] = wr[128 + lane]; w3[kk] = wr[192 + lane];
            }
#pragma unroll
            for (int p = 0; p < RPW; ++p) {
                const float4 iv = *reinterpret_cast<const float4*>(&sin_[lrow + p][k4 * 4]);
                ai[p] += iv.x * w0[0] + iv.y * w0[1] + iv.z * w0[2] + iv.w * w0[3];
                af[p] += iv.x * w1[0] + iv.y * w1[1] + iv.z * w1[2] + iv.w * w1[3];
                ag[p] += iv.x * w2[0] + iv.y * w2[1] + iv.z * w2[2] + iv.w * w2[3];
                ao[p] += iv.x * w3[0] + iv.y * w3[1] + iv.z * w3[2] + iv.w * w3[3];
            }
        }
        // ---- layer-2 update
#pragma unroll
        for (int p = 0; p < RPW; ++p) {
            float ig = sigmoidf_(ai[p]);
            float fg = sigmoidf_(af[p]);
            float gg = tanhf_(ag[p]);
            float og = sigmoidf_(ao[p]);
            float cv = fg * cB_r[p] + ig * gg;
            cB_r[p] = cv;
            hB_r[p] = og * tanhf_(cv);
        }
    }
    // ---- write final hidden states
#pragma unroll
    for (int p = 0; p < RPW; ++p) {
        hA[(size_t)(rbase + p) * 64 + lane] = hA_r[p];
        hB[(size_t)(rbase + p) * 64 + lane] = hB_r[p];
    }
}

// head: z = relu([hn1|hn2|skip] @ fc1^T + b1); out = relu(z @ fc2^T + b2). One wave per row.
__global__ void k_head(const float* __restrict__ hA, const float* __restrict__ hB,
                       const float* __restrict__ x, const float* __restrict__ fc1T,
                       const float* __restrict__ fc1b, const float* __restrict__ fc2w,
                       const float* __restrict__ fc2b, float* __restrict__ out) {
    int lane = threadIdx.x & 63, wv = threadIdx.x >> 6;
    int bn = blockIdx.x * 4 + wv;
    __shared__ float sz[4][208];
    int b = bn / NNODES, nn = bn - b * NNODES;
    for (int k = lane; k < 208; k += 64) {
        float v;
        if (k < 64) v = hA[(size_t)bn * 64 + k];
        else if (k < 128) v = hB[(size_t)bn * 64 + (k - 64)];
        else {
            int kk = k - 128;
            int w = kk >> 3, f = kk & 7;
            v = x[(size_t)((b * WINN + w) * NNODES + nn) * NFEAT + f];
        }
        sz[wv][k] = v;
    }
    __syncthreads();
    float acc = fc1b[lane];
    for (int k = 0; k < 208; ++k) acc += sz[wv][k] * fc1T[k * 64 + lane];
    acc = acc > 0.f ? acc : 0.f;
    float v = acc * fc2w[lane];
#pragma unroll
    for (int m = 32; m >= 1; m >>= 1) v += __shfl_xor(v, m, 64);
    if (lane == 0) {
        float z = v + fc2b[0];
        out[bn] = z > 0.f ? z : 0.f;
    }
}

// ---------------- launch ----------------
extern "C" void kernel_launch(void* const* d_in, const int* in_sizes, int n_in,
                              void* d_out, int out_size, void* d_ws, size_t ws_size,
                              hipStream_t stream) {
    const float* x     = (const float*)d_in[0];
    const int*   ei    = (const int*)d_in[1];
    const float* ew    = (const float*)d_in[2];
    const float* c1w   = (const float*)d_in[3];
    const float* c1b   = (const float*)d_in[4];
    const float* c2w   = (const float*)d_in[5];
    const float* c2b   = (const float*)d_in[6];
    const float* bn1g  = (const float*)d_in[7];
    const float* bn1b  = (const float*)d_in[8];
    const float* bn2g  = (const float*)d_in[9];
    const float* bn2b  = (const float*)d_in[10];
    const float* wih1  = (const float*)d_in[11];
    const float* whh1  = (const float*)d_in[12];
    const float* bih1  = (const float*)d_in[13];
    const float* bhh1  = (const float*)d_in[14];
    const float* wih2  = (const float*)d_in[15];
    const float* whh2  = (const float*)d_in[16];
    const float* bih2  = (const float*)d_in[17];
    const float* bhh2  = (const float*)d_in[18];
    const float* fc1w  = (const float*)d_in[19];
    const float* fc1b  = (const float*)d_in[20];
    const float* fc2w  = (const float*)d_in[21];
    const float* fc2b  = (const float*)d_in[22];
    float* out = (float*)d_out;

    float* ws = (float*)d_ws;
    size_t off = 0;
    auto A = [&](size_t n) { float* p = ws + off; off += n; return p; };
    float* dinv = A(NTOT);
    float* aggX = A((size_t)NTOT * NFEAT);   // layer-1 aggregate (8 ch)
    float* h1   = A((size_t)NTOT * 64);      // pre-BN -> h1 in place
    float* h2   = A((size_t)NTOT * 64);      // agg2 -> pre-BN -> h2 in place

    // ---- union region: CSR (GCN phase) aliases final LSTM states (LSTM phase) ----
    size_t uoff = off;
    float* hA   = A((size_t)NBN * 64);
    float* cAu  = A((size_t)NBN * 64);       // unused (kept for region sizing)
    float* hB   = A((size_t)NBN * 64);
    float* cBu  = A((size_t)NBN * 64);       // unused
    (void)cAu; (void)cBu;
    int2* epack = (int2*)(ws + uoff);                 // NEDGE int2 (8B aligned)
    int*  ptr   = (int*)(epack + NEDGE);              // NTOT+1
    int*  cur   = ptr + NTOT + 1;                     // NTOT (hist, then fill cursor)
    // CSR total = 2*NEDGE + 2*NTOT + 1 ints = 7.2M < 10.24M floats of union region

    float* wT1  = A(192 * 256);
    float* wT2  = A(128 * 256);
    float* b1   = A(256);
    float* b2   = A(256);
    float* fc1T = A(208 * 64);
    float* sums = A(2048);  // [0..127]=layer1; [128..1151]=layer2 8-copy
    float* ss1  = A(128);
    float* ss2  = A(128);
    float* scanTmpF = A(512);
    int* scanTmp = (int*)scanTmpF;
    // total ~65.1M floats = 248.5 MB <= 256 MiB ws

    if (ws_size < off * sizeof(float)) {
        k_diag<<<(out_size + 255) / 256, 256, 0, stream>>>(out, (float)ws_size, out_size);
        return;
    }

    constexpr int SCAN_NB = (NTOT + 1023) / 1024;   // 391

    // init + degree + CSR build
    k_init<<<(NTOT + 255) / 256, 256, 0, stream>>>(dinv, cur, sums);
    k_deg<<<NEDGE / 256, 256, 0, stream>>>(ei, ew, dinv, cur);
    k_dinv<<<(NTOT + 255) / 256, 256, 0, stream>>>(dinv);
    k_scan1<<<SCAN_NB, 256, 0, stream>>>(cur, ptr, scanTmp);
    k_scan2<<<1, 512, 0, stream>>>(scanTmp, SCAN_NB);
    k_scan3<<<(NTOT + 255) / 256, 256, 0, stream>>>(ptr, cur, scanTmp);
    k_fill<<<NEDGE / 256, 256, 0, stream>>>(ei, ew, dinv, cur, epack);
    k_prep<<<192, 256, 0, stream>>>(wih1, whh1, bih1, bhh1, wih2, whh2, bih2, bhh2,
                                    fc1w, wT1, b1, wT2, b2, fc1T);

    // ---- GCN layer 1: gather raw features (8 ch), then linear+relu+stats ----
    k_gather8<<<NTOT / 8 / 4, 256, 0, stream>>>(ptr, epack, x, dinv, aggX);
    k_lin1<<<512, 256, 0, stream>>>(aggX, c1w, c1b, h1, sums);
    k_bn_final<<<1, 64, 0, stream>>>(sums, bn1g, bn1b, ss1);
    k_bn_apply<<<2048, 256, 0, stream>>>(h1, ss1);

    // ---- GCN layer 2: gather h1 (64 ch, seed folded), then in-place linear+relu+stats ----
    k_gather64<<<NTOT / 4, 256, 0, stream>>>(ptr, epack, h1, dinv, h2);
    k_lin2b<<<2048, 256, 0, stream>>>(h2, c2w, c2b, sums + 128);
    k_bn_final8<<<1, 64, 0, stream>>>(sums + 128, bn2g, bn2b, ss2);
    k_bn_apply<<<2048, 256, 0, stream>>>(h2, ss2);

    // ---- persistent fused LSTM (states in registers, CSR region now dead) ----
    k_lstm_all<<<NBN / 64, 256, 0, stream>>>(h1, h2, wT1, wT2, b1, b2, hA, hB);

    // ---- head ----
    k_head<<<NBN / 4, 256, 0, stream>>>(hA, hB, x, fc1T, fc1b, fc2w, fc2b, out);
}

// Round 6
// 2339.839 us; speedup vs baseline: 2.4849x; 1.1388x over previous
//
#include <hip/hip_runtime.h>
#include <math.h>

// ---------------- problem constants ----------------
constexpr int BB     = 4;
constexpr int WINN   = 10;
constexpr int NNODES = 10000;
constexpr int NFEAT  = 8;
constexpr int NHID   = 64;
constexpr int NTOT   = BB * WINN * NNODES;   // 400000 stacked nodes
constexpr int NEDGE  = 3200000;
constexpr int NBN    = BB * NNODES;          // 40000 sequences
constexpr float EPSBN = 1e-5f;

#define DEVFN static __device__ __forceinline__

DEVFN float sigmoidf_(float x) { return 1.0f / (1.0f + __expf(-x)); }
// tanh(x) = 2*sigmoid(2x) - 1  (no inf/inf NaN; saturates correctly)
DEVFN float tanhf_(float x) { return 2.0f / (1.0f + __expf(-2.0f * x)) - 1.0f; }

// ---------------- diagnostic: report ws_size via output ----------------
__global__ void k_diag(float* out, float wsz, int n) {
    int i = blockIdx.x * 256 + threadIdx.x;
    if (i < n) out[i] = wsz;
}

// ---------------- init: deg=1 (self loop), zero hist + BN sums ----------------
__global__ void k_init(float* deg, int* cnt, float* sums) {
    int i = blockIdx.x * 256 + threadIdx.x;   // grid covers >= NTOT
    if (i < NTOT) { deg[i] = 1.0f; cnt[i] = 0; }
    if (i < 2048) sums[i] = 0.f;
}

// deg[col] += ew ; cnt[col]++   (weighted degree + in-degree histogram)
__global__ void k_deg(const int* __restrict__ ei, const float* __restrict__ ew,
                      float* deg, int* cnt) {
    int e = blockIdx.x * 256 + threadIdx.x;
    if (e < NEDGE) {
        int c = ei[NEDGE + e];
        atomicAdd(&deg[c], ew[e]);
        atomicAdd(&cnt[c], 1);
    }
}

__global__ void k_dinv(float* deg) {
    int i = blockIdx.x * 256 + threadIdx.x;
    if (i < NTOT) { float d = deg[i]; deg[i] = (d > 0.f) ? rsqrtf(d) : 0.f; }
}

// ---------------- exclusive scan of cnt -> ptr (1024 elems / block) ----------------
__global__ void k_scan1(const int* __restrict__ cnt, int* __restrict__ ptr, int* __restrict__ tmp) {
    __shared__ int sdat[256];
    int tid = threadIdx.x;
    int base = blockIdx.x * 1024 + tid * 4;
    int v0 = (base + 0 < NTOT) ? cnt[base + 0] : 0;
    int v1 = (base + 1 < NTOT) ? cnt[base + 1] : 0;
    int v2 = (base + 2 < NTOT) ? cnt[base + 2] : 0;
    int v3 = (base + 3 < NTOT) ? cnt[base + 3] : 0;
    int sum = v0 + v1 + v2 + v3;
    sdat[tid] = sum;
    __syncthreads();
    for (int ofs = 1; ofs < 256; ofs <<= 1) {
        int x = (tid >= ofs) ? sdat[tid - ofs] : 0;
        __syncthreads();
        sdat[tid] += x;
        __syncthreads();
    }
    int run = sdat[tid] - sum;   // exclusive prefix of this thread's 4
    if (base + 0 < NTOT) ptr[base + 0] = run; run += v0;
    if (base + 1 < NTOT) ptr[base + 1] = run; run += v1;
    if (base + 2 < NTOT) ptr[base + 2] = run; run += v2;
    if (base + 3 < NTOT) ptr[base + 3] = run;
    if (tid == 255) tmp[blockIdx.x] = sdat[255];
}

__global__ void k_scan2(int* tmp, int nb) {
    __shared__ int st[512];
    int tid = threadIdx.x;
    int v = (tid < nb) ? tmp[tid] : 0;
    st[tid] = v;
    __syncthreads();
    for (int ofs = 1; ofs < 512; ofs <<= 1) {
        int x = (tid >= ofs) ? st[tid - ofs] : 0;
        __syncthreads();
        st[tid] += x;
        __syncthreads();
    }
    if (tid < nb) tmp[tid] = st[tid] - v;   // exclusive
}

// add block offsets; copy ptr -> cur (fill cursor); write sentinel
__global__ void k_scan3(int* __restrict__ ptr, int* __restrict__ cur, const int* __restrict__ tmp) {
    int i = blockIdx.x * 256 + threadIdx.x;
    if (i < NTOT) {
        int p = ptr[i] + tmp[i >> 10];
        ptr[i] = p;
        cur[i] = p;
    }
    if (i == 0) ptr[NTOT] = NEDGE;
}

// CSR fill: epack[pos] = (row, norm) grouped by destination col
__global__ void k_fill(const int* __restrict__ ei, const float* __restrict__ ew,
                       const float* __restrict__ dinv, int* __restrict__ cur,
                       int2* __restrict__ epack) {
    int e = blockIdx.x * 256 + threadIdx.x;
    if (e >= NEDGE) return;
    int row = ei[e], col = ei[NEDGE + e];
    float nv = dinv[row] * ew[e] * dinv[col];
    int pos = atomicAdd(&cur[col], 1);
    epack[pos] = make_int2(row, __float_as_int(nv));
}

// layer-1 gather over raw features (8 ch): one 8-lane group per node, 8 nodes/wave
__global__ void k_gather8(const int* __restrict__ ptr, const int2* __restrict__ epack,
                          const float* __restrict__ x, const float* __restrict__ dinv,
                          float* __restrict__ aggX) {
    int tid = threadIdx.x;
    int lane = tid & 63;
    int waveg = blockIdx.x * 4 + (tid >> 6);      // grid exact: NTOT/8 waves
    int g = lane >> 3, ch = lane & 7;
    int node = waveg * 8 + g;
    int beg = ptr[node], end = ptr[node + 1];
    float dv = dinv[node];
    float acc = dv * dv * x[node * 8 + ch];
    int e = beg;
    for (; e + 1 < end; e += 2) {
        int2 p0 = epack[e], p1 = epack[e + 1];
        acc = fmaf(__int_as_float(p0.y), x[p0.x * 8 + ch], acc);
        acc = fmaf(__int_as_float(p1.y), x[p1.x * 8 + ch], acc);
    }
    if (e < end) {
        int2 p = epack[e];
        acc = fmaf(__int_as_float(p.y), x[p.x * 8 + ch], acc);
    }
    aggX[node * 8 + ch] = acc;
}

// layer-2 gather (64 ch) with self-loop seed folded in: one wave per node
__global__ void k_gather64(const int* __restrict__ ptr, const int2* __restrict__ epack,
                           const float* __restrict__ src, const float* __restrict__ dinv,
                           float* __restrict__ dst) {
    int lane = threadIdx.x & 63;
    int node = blockIdx.x * 4 + (threadIdx.x >> 6);   // grid exact: NTOT/4 blocks
    int beg = ptr[node], end = ptr[node + 1];
    float dv = dinv[node];
    float acc = dv * dv * src[(size_t)node * 64 + lane];
    int e = beg;
    for (; e + 1 < end; e += 2) {
        int2 p0 = epack[e], p1 = epack[e + 1];
        acc = fmaf(__int_as_float(p0.y), src[(size_t)p0.x * 64 + lane], acc);
        acc = fmaf(__int_as_float(p1.y), src[(size_t)p1.x * 64 + lane], acc);
    }
    if (e < end) {
        int2 p = epack[e];
        acc = fmaf(__int_as_float(p.y), src[(size_t)p.x * 64 + lane], acc);
    }
    dst[(size_t)node * 64 + lane] = acc;
}

// h1 = relu(aggX @ W1 + b) + per-channel BN stats (sum, sumsq)
__global__ void k_lin1(const float* __restrict__ aggX, const float* __restrict__ W,
                       const float* __restrict__ bias, float* __restrict__ h1,
                       float* __restrict__ sums) {
    __shared__ float sW[NFEAT * NHID];        // 512 floats
    int tid = threadIdx.x;
    sW[tid] = W[tid];
    sW[tid + 256] = W[tid + 256];
    __syncthreads();
    int c = tid & 63;                         // stride % 64 == 0 -> channel constant
    float b = bias[c];
    float s = 0.f, sq = 0.f;
    int stride = gridDim.x * 256;
    for (int i = blockIdx.x * 256 + tid; i < NTOT * 64; i += stride) {
        int n = i >> 6;
        float acc = b;
#pragma unroll
        for (int f = 0; f < NFEAT; ++f) acc = fmaf(aggX[n * NFEAT + f], sW[f * NHID + c], acc);
        acc = acc > 0.f ? acc : 0.f;
        h1[i] = acc;
        s += acc;
        sq = fmaf(acc, acc, sq);
    }
    __shared__ float ls[4][64], lq[4][64];
    int w = tid >> 6;
    ls[w][c] = s; lq[w][c] = sq;
    __syncthreads();
    if (tid < 64) {
        atomicAdd(&sums[tid], ls[0][tid] + ls[1][tid] + ls[2][tid] + ls[3][tid]);
        atomicAdd(&sums[64 + tid], lq[0][tid] + lq[1][tid] + lq[2][tid] + lq[3][tid]);
    }
}

// per-channel scale/shift from sums (single accumulator copy)
__global__ void k_bn_final(const float* __restrict__ sums, const float* __restrict__ g,
                           const float* __restrict__ b, float* __restrict__ ss) {
    int i = threadIdx.x;
    if (i >= 64) return;
    float mean = sums[i] * (1.0f / NTOT);
    float var = sums[64 + i] * (1.0f / NTOT) - mean * mean;
    float sc = g[i] * rsqrtf(var + EPSBN);
    ss[i] = sc;
    ss[64 + i] = b[i] - mean * sc;
}

// per-channel scale/shift from 8 spread accumulator copies
__global__ void k_bn_final8(const float* __restrict__ sums8, const float* __restrict__ g,
                            const float* __restrict__ b, float* __restrict__ ss) {
    int i = threadIdx.x;
    if (i >= 64) return;
    float S = 0.f, Q = 0.f;
#pragma unroll
    for (int m = 0; m < 8; ++m) { S += sums8[m * 128 + i]; Q += sums8[m * 128 + 64 + i]; }
    float mean = S * (1.0f / NTOT);
    float var = Q * (1.0f / NTOT) - mean * mean;
    float sc = g[i] * rsqrtf(var + EPSBN);
    ss[i] = sc;
    ss[64 + i] = b[i] - mean * sc;
}

// io = io*sc[c] + sh[c] in place
__global__ void k_bn_apply(float* __restrict__ io, const float* __restrict__ ss) {
    int c = threadIdx.x & 63;
    float sc = ss[c], sh = ss[64 + c];
    int stride = gridDim.x * 256;
    for (int i = blockIdx.x * 256 + threadIdx.x; i < NTOT * 64; i += stride)
        io[i] = fmaf(io[i], sc, sh);
}

// fold BN2 affine into LSTM layer-1 weights (h2 input cols 64..127) + bias
__global__ void k_fold(float* __restrict__ wT1, float* __restrict__ b1,
                       const float* __restrict__ ss2) {
    int j = threadIdx.x;   // 256 gate outputs
    float acc = 0.f;
#pragma unroll
    for (int m = 0; m < 64; ++m) {
        float w = wT1[(64 + m) * 256 + j];
        acc = fmaf(w, ss2[64 + m], acc);
        wT1[(64 + m) * 256 + j] = w * ss2[m];
    }
    b1[j] += acc;
}

// in-place row = relu(row @ W2 + b): LDS-staged broadcast (no scalar-load chain)
__global__ void k_lin2b(float* __restrict__ io, const float* __restrict__ W2,
                        const float* __restrict__ bias, float* __restrict__ sums8) {
    __shared__ __align__(16) float srow[4][64];
    __shared__ float ls[4][64], lq[4][64];
    int lane = threadIdx.x & 63, wv = threadIdx.x >> 6;
    float wc[64];
#pragma unroll
    for (int h = 0; h < 64; ++h) wc[h] = W2[h * 64 + lane];
    float b = bias[lane];
    float s = 0.f, sq = 0.f;
    int wid = blockIdx.x * 4 + wv;
    int nw = gridDim.x * 4;
    for (int row = wid; row < NTOT; row += nw) {
        float* hr = io + (size_t)row * 64;
        srow[wv][lane] = hr[lane];            // coalesced 256B load -> LDS
        float acc = b;
#pragma unroll
        for (int h4 = 0; h4 < 16; ++h4) {     // broadcast float4 reads
            float4 iv = *reinterpret_cast<const float4*>(&srow[wv][h4 * 4]);
            acc = fmaf(iv.x, wc[h4 * 4 + 0], acc);
            acc = fmaf(iv.y, wc[h4 * 4 + 1], acc);
            acc = fmaf(iv.z, wc[h4 * 4 + 2], acc);
            acc = fmaf(iv.w, wc[h4 * 4 + 3], acc);
        }
        acc = acc > 0.f ? acc : 0.f;
        hr[lane] = acc;
        s += acc;
        sq = fmaf(acc, acc, sq);
    }
    ls[wv][lane] = s; lq[wv][lane] = sq;
    __syncthreads();
    if (threadIdx.x < 64) {
        float S = ls[0][lane] + ls[1][lane] + ls[2][lane] + ls[3][lane];
        float Q = lq[0][lane] + lq[1][lane] + lq[2][lane] + lq[3][lane];
        float* dst = sums8 + (blockIdx.x & 7) * 128;
        atomicAdd(&dst[lane], S);
        atomicAdd(&dst[64 + lane], Q);
    }
}

// transpose/fuse LSTM + FC1 weights
__global__ void k_prep(const float* __restrict__ wih1, const float* __restrict__ whh1,
                       const float* __restrict__ bih1, const float* __restrict__ bhh1,
                       const float* __restrict__ wih2, const float* __restrict__ whh2,
                       const float* __restrict__ bih2, const float* __restrict__ bhh2,
                       const float* __restrict__ fc1w,
                       float* wT1, float* b1, float* wT2, float* b2, float* fc1T) {
    int i = blockIdx.x * 256 + threadIdx.x;
    if (i < 192 * 256) {
        int k = i >> 8, j = i & 255;
        wT1[i] = (k < 128) ? wih1[j * 128 + k] : whh1[j * 64 + (k - 128)];
    }
    if (i < 128 * 256) {
        int k = i >> 8, j = i & 255;
        wT2[i] = (k < 64) ? wih2[j * 64 + k] : whh2[j * 64 + (k - 64)];
    }
    if (i < 208 * 64) {
        int k = i >> 6, o = i & 63;
        fc1T[i] = fc1w[o * 208 + k];
    }
    if (i < 256) { b1[i] = bih1[i] + bhh1[i]; b2[i] = bih2[i] + bhh2[i]; }
}

// ---------------- persistent fused 2-layer LSTM, all 10 timesteps ----------------
// Block = 2 waves, 32 rows (grid 1250 for load balance); wave owns 16 rows all t.
// States h/c (both layers) in registers; per-t inputs staged in per-wave LDS slice.
// Lane j owns hidden unit j (gates j, j+64, j+128, j+192).
__global__ __launch_bounds__(128) void k_lstm_all(
    const float* __restrict__ h1, const float* __restrict__ h2,
    const float* __restrict__ wT1, const float* __restrict__ wT2,
    const float* __restrict__ bs1, const float* __restrict__ bs2,
    float* __restrict__ hA, float* __restrict__ hB) {
    constexpr int RPW = 16;
    __shared__ __align__(16) float sin_[32][192];   // 24 KB
    int tid = threadIdx.x;
    int lane = tid & 63, wv = tid >> 6;
    int lrow = wv * RPW;                      // wave's LDS row base
    int rbase = blockIdx.x * 32 + lrow;       // wave's first global row (bn)

    float hA_r[RPW], cA_r[RPW], hB_r[RPW], cB_r[RPW];
#pragma unroll
    for (int p = 0; p < RPW; ++p) { hA_r[p] = 0.f; cA_r[p] = 0.f; hB_r[p] = 0.f; cB_r[p] = 0.f; }

    float b1i = bs1[lane], b1f = bs1[64 + lane], b1g = bs1[128 + lane], b1o = bs1[192 + lane];
    float b2i = bs2[lane], b2f = bs2[64 + lane], b2g = bs2[128 + lane], b2o = bs2[192 + lane];

    for (int t = 0; t < WINN; ++t) {
        // ---- stage layer-1 input [h1(node)|h2(node)] into cols 0..127 (wave-local rows)
#pragma unroll
        for (int it = 0; it < 8; ++it) {
            int idx = it * 64 + lane;         // 0..511 = 16 rows * 32 float4
            int r = idx >> 5, f = idx & 31;
            int bn = rbase + r;
            int b = bn / NNODES, nn = bn - b * NNODES;
            size_t node = (size_t)((b * WINN + t) * NNODES + nn);
            float4 v = (f < 16) ? reinterpret_cast<const float4*>(h1)[node * 16 + f]
                                : reinterpret_cast<const float4*>(h2)[node * 16 + (f - 16)];
            *reinterpret_cast<float4*>(&sin_[lrow + r][f * 4]) = v;
        }
        // own h_layer1 -> cols 128..191
#pragma unroll
        for (int p = 0; p < RPW; ++p) sin_[lrow + p][128 + lane] = hA_r[p];

        // ---- layer-1 gates (K = 192)
        float ai[RPW], af[RPW], ag[RPW], ao[RPW];
#pragma unroll
        for (int p = 0; p < RPW; ++p) { ai[p] = b1i; af[p] = b1f; ag[p] = b1g; ao[p] = b1o; }
        for (int k4 = 0; k4 < 48; ++k4) {
            float w0[4], w1[4], w2[4], w3[4];
#pragma unroll
            for (int kk = 0; kk < 4; ++kk) {
                const float* wr = wT1 + (k4 * 4 + kk) * 256;
                w0[kk] = wr[lane]; w1[kk] = wr[64 + lane];
                w2[kk] = wr[128 + lane]; w3[kk] = wr[192 + lane];
            }
#pragma unroll
            for (int p = 0; p < RPW; ++p) {
                const float4 iv = *reinterpret_cast<const float4*>(&sin_[lrow + p][k4 * 4]);
                ai[p] = fmaf(iv.x, w0[0], ai[p]); ai[p] = fmaf(iv.y, w0[1], ai[p]);
                ai[p] = fmaf(iv.z, w0[2], ai[p]); ai[p] = fmaf(iv.w, w0[3], ai[p]);
                af[p] = fmaf(iv.x, w1[0], af[p]); af[p] = fmaf(iv.y, w1[1], af[p]);
                af[p] = fmaf(iv.z, w1[2], af[p]); af[p] = fmaf(iv.w, w1[3], af[p]);
                ag[p] = fmaf(iv.x, w2[0], ag[p]); ag[p] = fmaf(iv.y, w2[1], ag[p]);
                ag[p] = fmaf(iv.z, w2[2], ag[p]); ag[p] = fmaf(iv.w, w2[3], ag[p]);
                ao[p] = fmaf(iv.x, w3[0], ao[p]); ao[p] = fmaf(iv.y, w3[1], ao[p]);
                ao[p] = fmaf(iv.z, w3[2], ao[p]); ao[p] = fmaf(iv.w, w3[3], ao[p]);
            }
        }
        // ---- layer-1 update; stage layer-2 input [h_l1|hB] into cols 0..127
#pragma unroll
        for (int p = 0; p < RPW; ++p) {
            float ig = sigmoidf_(ai[p]);
            float fg = sigmoidf_(af[p]);
            float gg = tanhf_(ag[p]);
            float og = sigmoidf_(ao[p]);
            float cv = fmaf(fg, cA_r[p], ig * gg);
            cA_r[p] = cv;
            float hv = og * tanhf_(cv);
            hA_r[p] = hv;
            sin_[lrow + p][lane] = hv;
            sin_[lrow + p][64 + lane] = hB_r[p];
        }
        // ---- layer-2 gates (K = 128)
#pragma unroll
        for (int p = 0; p < RPW; ++p) { ai[p] = b2i; af[p] = b2f; ag[p] = b2g; ao[p] = b2o; }
        for (int k4 = 0; k4 < 32; ++k4) {
            float w0[4], w1[4], w2[4], w3[4];
#pragma unroll
            for (int kk = 0; kk < 4; ++kk) {
                const float* wr = wT2 + (k4 * 4 + kk) * 256;
                w0[kk] = wr[lane]; w1[kk] = wr[64 + lane];
                w2[kk] = wr[128 + lane]; w3[kk] = wr[192 + lane];
            }
#pragma unroll
            for (int p = 0; p < RPW; ++p) {
                const float4 iv = *reinterpret_cast<const float4*>(&sin_[lrow + p][k4 * 4]);
                ai[p] = fmaf(iv.x, w0[0], ai[p]); ai[p] = fmaf(iv.y, w0[1], ai[p]);
                ai[p] = fmaf(iv.z, w0[2], ai[p]); ai[p] = fmaf(iv.w, w0[3], ai[p]);
                af[p] = fmaf(iv.x, w1[0], af[p]); af[p] = fmaf(iv.y, w1[1], af[p]);
                af[p] = fmaf(iv.z, w1[2], af[p]); af[p] = fmaf(iv.w, w1[3], af[p]);
                ag[p] = fmaf(iv.x, w2[0], ag[p]); ag[p] = fmaf(iv.y, w2[1], ag[p]);
                ag[p] = fmaf(iv.z, w2[2], ag[p]); ag[p] = fmaf(iv.w, w2[3], ag[p]);
                ao[p] = fmaf(iv.x, w3[0], ao[p]); ao[p] = fmaf(iv.y, w3[1], ao[p]);
                ao[p] = fmaf(iv.z, w3[2], ao[p]); ao[p] = fmaf(iv.w, w3[3], ao[p]);
            }
        }
        // ---- layer-2 update
#pragma unroll
        for (int p = 0; p < RPW; ++p) {
            float ig = sigmoidf_(ai[p]);
            float fg = sigmoidf_(af[p]);
            float gg = tanhf_(ag[p]);
            float og = sigmoidf_(ao[p]);
            float cv = fmaf(fg, cB_r[p], ig * gg);
            cB_r[p] = cv;
            hB_r[p] = og * tanhf_(cv);
        }
    }
    // ---- write final hidden states
#pragma unroll
    for (int p = 0; p < RPW; ++p) {
        hA[(size_t)(rbase + p) * 64 + lane] = hA_r[p];
        hB[(size_t)(rbase + p) * 64 + lane] = hB_r[p];
    }
}

// head: z = relu([hn1|hn2|skip] @ fc1^T + b1); out = relu(z @ fc2^T + b2). One wave per row.
__global__ void k_head(const float* __restrict__ hA, const float* __restrict__ hB,
                       const float* __restrict__ x, const float* __restrict__ fc1T,
                       const float* __restrict__ fc1b, const float* __restrict__ fc2w,
                       const float* __restrict__ fc2b, float* __restrict__ out) {
    int lane = threadIdx.x & 63, wv = threadIdx.x >> 6;
    int bn = blockIdx.x * 4 + wv;
    __shared__ float sz[4][208];
    int b = bn / NNODES, nn = bn - b * NNODES;
    for (int k = lane; k < 208; k += 64) {
        float v;
        if (k < 64) v = hA[(size_t)bn * 64 + k];
        else if (k < 128) v = hB[(size_t)bn * 64 + (k - 64)];
        else {
            int kk = k - 128;
            int w = kk >> 3, f = kk & 7;
            v = x[(size_t)((b * WINN + w) * NNODES + nn) * NFEAT + f];
        }
        sz[wv][k] = v;
    }
    __syncthreads();
    float acc = fc1b[lane];
    for (int k = 0; k < 208; ++k) acc = fmaf(sz[wv][k], fc1T[k * 64 + lane], acc);
    acc = acc > 0.f ? acc : 0.f;
    float v = acc * fc2w[lane];
#pragma unroll
    for (int m = 32; m >= 1; m >>= 1) v += __shfl_xor(v, m, 64);
    if (lane == 0) {
        float z = v + fc2b[0];
        out[bn] = z > 0.f ? z : 0.f;
    }
}

// ---------------- launch ----------------
extern "C" void kernel_launch(void* const* d_in, const int* in_sizes, int n_in,
                              void* d_out, int out_size, void* d_ws, size_t ws_size,
                              hipStream_t stream) {
    const float* x     = (const float*)d_in[0];
    const int*   ei    = (const int*)d_in[1];
    const float* ew    = (const float*)d_in[2];
    const float* c1w   = (const float*)d_in[3];
    const float* c1b   = (const float*)d_in[4];
    const float* c2w   = (const float*)d_in[5];
    const float* c2b   = (const float*)d_in[6];
    const float* bn1g  = (const float*)d_in[7];
    const float* bn1b  = (const float*)d_in[8];
    const float* bn2g  = (const float*)d_in[9];
    const float* bn2b  = (const float*)d_in[10];
    const float* wih1  = (const float*)d_in[11];
    const float* whh1  = (const float*)d_in[12];
    const float* bih1  = (const float*)d_in[13];
    const float* bhh1  = (const float*)d_in[14];
    const float* wih2  = (const float*)d_in[15];
    const float* whh2  = (const float*)d_in[16];
    const float* bih2  = (const float*)d_in[17];
    const float* bhh2  = (const float*)d_in[18];
    const float* fc1w  = (const float*)d_in[19];
    const float* fc1b  = (const float*)d_in[20];
    const float* fc2w  = (const float*)d_in[21];
    const float* fc2b  = (const float*)d_in[22];
    float* out = (float*)d_out;

    float* ws = (float*)d_ws;
    size_t off = 0;
    auto A = [&](size_t n) { float* p = ws + off; off += n; return p; };
    float* dinv = A(NTOT);
    float* aggX = A((size_t)NTOT * NFEAT);   // layer-1 aggregate (8 ch)
    float* h1   = A((size_t)NTOT * 64);      // pre-BN -> h1 in place
    float* h2   = A((size_t)NTOT * 64);      // agg2 -> relu'd (BN2 folded into LSTM weights)

    // ---- union region: CSR (GCN phase) aliases final LSTM states (LSTM phase) ----
    size_t uoff = off;
    float* hA   = A((size_t)NBN * 64);
    float* cAu  = A((size_t)NBN * 64);       // unused (kept for region sizing)
    float* hB   = A((size_t)NBN * 64);
    float* cBu  = A((size_t)NBN * 64);       // unused
    (void)cAu; (void)cBu;
    int2* epack = (int2*)(ws + uoff);                 // NEDGE int2 (8B aligned)
    int*  ptr   = (int*)(epack + NEDGE);              // NTOT+1
    int*  cur   = ptr + NTOT + 1;                     // NTOT (hist, then fill cursor)
    // CSR total = 2*NEDGE + 2*NTOT + 1 ints = 7.2M < 10.24M floats of union region

    float* wT1  = A(192 * 256);
    float* wT2  = A(128 * 256);
    float* b1   = A(256);
    float* b2   = A(256);
    float* fc1T = A(208 * 64);
    float* sums = A(2048);  // [0..127]=layer1; [128..1151]=layer2 8-copy
    float* ss1  = A(128);
    float* ss2  = A(128);
    float* scanTmpF = A(512);
    int* scanTmp = (int*)scanTmpF;
    // total ~65.1M floats = 248.5 MB <= 256 MiB ws

    if (ws_size < off * sizeof(float)) {
        k_diag<<<(out_size + 255) / 256, 256, 0, stream>>>(out, (float)ws_size, out_size);
        return;
    }

    constexpr int SCAN_NB = (NTOT + 1023) / 1024;   // 391

    // init + degree + CSR build
    k_init<<<(NTOT + 255) / 256, 256, 0, stream>>>(dinv, cur, sums);
    k_deg<<<NEDGE / 256, 256, 0, stream>>>(ei, ew, dinv, cur);
    k_dinv<<<(NTOT + 255) / 256, 256, 0, stream>>>(dinv);
    k_scan1<<<SCAN_NB, 256, 0, stream>>>(cur, ptr, scanTmp);
    k_scan2<<<1, 512, 0, stream>>>(scanTmp, SCAN_NB);
    k_scan3<<<(NTOT + 255) / 256, 256, 0, stream>>>(ptr, cur, scanTmp);
    k_fill<<<NEDGE / 256, 256, 0, stream>>>(ei, ew, dinv, cur, epack);
    k_prep<<<192, 256, 0, stream>>>(wih1, whh1, bih1, bhh1, wih2, whh2, bih2, bhh2,
                                    fc1w, wT1, b1, wT2, b2, fc1T);

    // ---- GCN layer 1: gather raw features (8 ch), then linear+relu+stats ----
    k_gather8<<<NTOT / 8 / 4, 256, 0, stream>>>(ptr, epack, x, dinv, aggX);
    k_lin1<<<512, 256, 0, stream>>>(aggX, c1w, c1b, h1, sums);
    k_bn_final<<<1, 64, 0, stream>>>(sums, bn1g, bn1b, ss1);
    k_bn_apply<<<2048, 256, 0, stream>>>(h1, ss1);

    // ---- GCN layer 2: gather h1 (64 ch, seed folded), then in-place linear+relu+stats ----
    // h2 stays pre-BN (post-relu); BN2 affine folded into wT1/b1 by k_fold.
    k_gather64<<<NTOT / 4, 256, 0, stream>>>(ptr, epack, h1, dinv, h2);
    k_lin2b<<<2048, 256, 0, stream>>>(h2, c2w, c2b, sums + 128);
    k_bn_final8<<<1, 64, 0, stream>>>(sums + 128, bn2g, bn2b, ss2);
    k_fold<<<1, 256, 0, stream>>>(wT1, b1, ss2);

    // ---- persistent fused LSTM (states in registers, CSR region now dead) ----
    k_lstm_all<<<NBN / 32, 128, 0, stream>>>(h1, h2, wT1, wT2, b1, b2, hA, hB);

    // ---- head ----
    k_head<<<NBN / 4, 256, 0, stream>>>(hA, hB, x, fc1T, fc1b, fc2w, fc2b, out);
}

// Round 7
// 2278.901 us; speedup vs baseline: 2.5514x; 1.0267x over previous
//
#include <hip/hip_runtime.h>
#include <math.h>

// ---------------- problem constants ----------------
constexpr int BB     = 4;
constexpr int WINN   = 10;
constexpr int NNODES = 10000;
constexpr int NFEAT  = 8;
constexpr int NHID   = 64;
constexpr int NTOT   = BB * WINN * NNODES;   // 400000 stacked nodes
constexpr int NEDGE  = 3200000;
constexpr int NBN    = BB * NNODES;          // 40000 sequences
constexpr float EPSBN = 1e-5f;

#define DEVFN static __device__ __forceinline__

typedef float f4 __attribute__((ext_vector_type(4)));
typedef short s8v __attribute__((ext_vector_type(8)));
typedef unsigned short ushort_t;
typedef unsigned int uint_t;

DEVFN float sigmoidf_(float x) { return 1.0f / (1.0f + __expf(-x)); }
DEVFN float tanhf_(float x) { return 2.0f / (1.0f + __expf(-2.0f * x)) - 1.0f; }
DEVFN ushort_t f2bf(float f) {             // round-to-nearest-even bf16
    uint_t x = __float_as_uint(f);
    return (ushort_t)((x + 0x7FFFu + ((x >> 16) & 1u)) >> 16);
}
DEVFN float bf2f(ushort_t u) { return __uint_as_float(((uint_t)u) << 16); }

// ---------------- diagnostic ----------------
__global__ void k_diag(float* out, float wsz, int n) {
    int i = blockIdx.x * 256 + threadIdx.x;
    if (i < n) out[i] = wsz;
}

// ---------------- init ----------------
__global__ void k_init(float* deg, int* cnt, float* sums) {
    int i = blockIdx.x * 256 + threadIdx.x;
    if (i < NTOT) { deg[i] = 1.0f; cnt[i] = 0; }
    if (i < 2048) sums[i] = 0.f;
}

__global__ void k_deg(const int* __restrict__ ei, const float* __restrict__ ew,
                      float* deg, int* cnt) {
    int e = blockIdx.x * 256 + threadIdx.x;
    if (e < NEDGE) {
        int c = ei[NEDGE + e];
        atomicAdd(&deg[c], ew[e]);
        atomicAdd(&cnt[c], 1);
    }
}

__global__ void k_dinv(float* deg) {
    int i = blockIdx.x * 256 + threadIdx.x;
    if (i < NTOT) { float d = deg[i]; deg[i] = (d > 0.f) ? rsqrtf(d) : 0.f; }
}

// ---------------- scan ----------------
__global__ void k_scan1(const int* __restrict__ cnt, int* __restrict__ ptr, int* __restrict__ tmp) {
    __shared__ int sdat[256];
    int tid = threadIdx.x;
    int base = blockIdx.x * 1024 + tid * 4;
    int v0 = (base + 0 < NTOT) ? cnt[base + 0] : 0;
    int v1 = (base + 1 < NTOT) ? cnt[base + 1] : 0;
    int v2 = (base + 2 < NTOT) ? cnt[base + 2] : 0;
    int v3 = (base + 3 < NTOT) ? cnt[base + 3] : 0;
    int sum = v0 + v1 + v2 + v3;
    sdat[tid] = sum;
    __syncthreads();
    for (int ofs = 1; ofs < 256; ofs <<= 1) {
        int x = (tid >= ofs) ? sdat[tid - ofs] : 0;
        __syncthreads();
        sdat[tid] += x;
        __syncthreads();
    }
    int run = sdat[tid] - sum;
    if (base + 0 < NTOT) ptr[base + 0] = run; run += v0;
    if (base + 1 < NTOT) ptr[base + 1] = run; run += v1;
    if (base + 2 < NTOT) ptr[base + 2] = run; run += v2;
    if (base + 3 < NTOT) ptr[base + 3] = run;
    if (tid == 255) tmp[blockIdx.x] = sdat[255];
}

__global__ void k_scan2(int* tmp, int nb) {
    __shared__ int st[512];
    int tid = threadIdx.x;
    int v = (tid < nb) ? tmp[tid] : 0;
    st[tid] = v;
    __syncthreads();
    for (int ofs = 1; ofs < 512; ofs <<= 1) {
        int x = (tid >= ofs) ? st[tid - ofs] : 0;
        __syncthreads();
        st[tid] += x;
        __syncthreads();
    }
    if (tid < nb) tmp[tid] = st[tid] - v;
}

__global__ void k_scan3(int* __restrict__ ptr, int* __restrict__ cur, const int* __restrict__ tmp) {
    int i = blockIdx.x * 256 + threadIdx.x;
    if (i < NTOT) {
        int p = ptr[i] + tmp[i >> 10];
        ptr[i] = p;
        cur[i] = p;
    }
    if (i == 0) ptr[NTOT] = NEDGE;
}

__global__ void k_fill(const int* __restrict__ ei, const float* __restrict__ ew,
                       const float* __restrict__ dinv, int* __restrict__ cur,
                       int2* __restrict__ epack) {
    int e = blockIdx.x * 256 + threadIdx.x;
    if (e >= NEDGE) return;
    int row = ei[e], col = ei[NEDGE + e];
    float nv = dinv[row] * ew[e] * dinv[col];
    int pos = atomicAdd(&cur[col], 1);
    epack[pos] = make_int2(row, __float_as_int(nv));
}

// layer-1 gather over raw features (8 ch)
__global__ void k_gather8(const int* __restrict__ ptr, const int2* __restrict__ epack,
                          const float* __restrict__ x, const float* __restrict__ dinv,
                          float* __restrict__ aggX) {
    int tid = threadIdx.x;
    int lane = tid & 63;
    int waveg = blockIdx.x * 4 + (tid >> 6);
    int g = lane >> 3, ch = lane & 7;
    int node = waveg * 8 + g;
    int beg = ptr[node], end = ptr[node + 1];
    float dv = dinv[node];
    float acc = dv * dv * x[node * 8 + ch];
    int e = beg;
    for (; e + 1 < end; e += 2) {
        int2 p0 = epack[e], p1 = epack[e + 1];
        acc = fmaf(__int_as_float(p0.y), x[p0.x * 8 + ch], acc);
        acc = fmaf(__int_as_float(p1.y), x[p1.x * 8 + ch], acc);
    }
    if (e < end) {
        int2 p = epack[e];
        acc = fmaf(__int_as_float(p.y), x[p.x * 8 + ch], acc);
    }
    aggX[node * 8 + ch] = acc;
}

// layer-2 gather (64 ch) from bf16 h1, self-loop folded
__global__ void k_gather64(const int* __restrict__ ptr, const int2* __restrict__ epack,
                           const ushort_t* __restrict__ src, const float* __restrict__ dinv,
                           float* __restrict__ dst) {
    int lane = threadIdx.x & 63;
    int node = blockIdx.x * 4 + (threadIdx.x >> 6);
    int beg = ptr[node], end = ptr[node + 1];
    float dv = dinv[node];
    float acc = dv * dv * bf2f(src[(size_t)node * 64 + lane]);
    int e = beg;
    for (; e + 1 < end; e += 2) {
        int2 p0 = epack[e], p1 = epack[e + 1];
        acc = fmaf(__int_as_float(p0.y), bf2f(src[(size_t)p0.x * 64 + lane]), acc);
        acc = fmaf(__int_as_float(p1.y), bf2f(src[(size_t)p1.x * 64 + lane]), acc);
    }
    if (e < end) {
        int2 p = epack[e];
        acc = fmaf(__int_as_float(p.y), bf2f(src[(size_t)p.x * 64 + lane]), acc);
    }
    dst[(size_t)node * 64 + lane] = acc;
}

// preH1 = relu(aggX @ W1 + b) + BN stats
__global__ void k_lin1(const float* __restrict__ aggX, const float* __restrict__ W,
                       const float* __restrict__ bias, float* __restrict__ h1,
                       float* __restrict__ sums) {
    __shared__ float sW[NFEAT * NHID];
    int tid = threadIdx.x;
    sW[tid] = W[tid];
    sW[tid + 256] = W[tid + 256];
    __syncthreads();
    int c = tid & 63;
    float b = bias[c];
    float s = 0.f, sq = 0.f;
    int stride = gridDim.x * 256;
    for (int i = blockIdx.x * 256 + tid; i < NTOT * 64; i += stride) {
        int n = i >> 6;
        float acc = b;
#pragma unroll
        for (int f = 0; f < NFEAT; ++f) acc = fmaf(aggX[n * NFEAT + f], sW[f * NHID + c], acc);
        acc = acc > 0.f ? acc : 0.f;
        h1[i] = acc;
        s += acc;
        sq = fmaf(acc, acc, sq);
    }
    __shared__ float ls[4][64], lq[4][64];
    int w = tid >> 6;
    ls[w][c] = s; lq[w][c] = sq;
    __syncthreads();
    if (tid < 64) {
        atomicAdd(&sums[tid], ls[0][tid] + ls[1][tid] + ls[2][tid] + ls[3][tid]);
        atomicAdd(&sums[64 + tid], lq[0][tid] + lq[1][tid] + lq[2][tid] + lq[3][tid]);
    }
}

__global__ void k_bn_final(const float* __restrict__ sums, const float* __restrict__ g,
                           const float* __restrict__ b, float* __restrict__ ss) {
    int i = threadIdx.x;
    if (i >= 64) return;
    float mean = sums[i] * (1.0f / NTOT);
    float var = sums[64 + i] * (1.0f / NTOT) - mean * mean;
    float sc = g[i] * rsqrtf(var + EPSBN);
    ss[i] = sc;
    ss[64 + i] = b[i] - mean * sc;
}

__global__ void k_bn_final8(const float* __restrict__ sums8, const float* __restrict__ g,
                            const float* __restrict__ b, float* __restrict__ ss) {
    int i = threadIdx.x;
    if (i >= 64) return;
    float S = 0.f, Q = 0.f;
#pragma unroll
    for (int m = 0; m < 8; ++m) { S += sums8[m * 128 + i]; Q += sums8[m * 128 + 64 + i]; }
    float mean = S * (1.0f / NTOT);
    float var = Q * (1.0f / NTOT) - mean * mean;
    float sc = g[i] * rsqrtf(var + EPSBN);
    ss[i] = sc;
    ss[64 + i] = b[i] - mean * sc;
}

// h1bf = bf16(preH1*sc + sh)   (BN1 apply + cast)
__global__ void k_bn1cast(const float* __restrict__ pre, const float* __restrict__ ss,
                          ushort_t* __restrict__ dst) {
    int c = threadIdx.x & 63;
    float sc = ss[c], sh = ss[64 + c];
    int stride = gridDim.x * 256;
    for (int i = blockIdx.x * 256 + threadIdx.x; i < NTOT * 64; i += stride)
        dst[i] = f2bf(fmaf(pre[i], sc, sh));
}

// h2bf = bf16(relu(row @ W2 + b)) + BN stats (pre-BN; BN2 folded into LSTM weights)
__global__ void k_lin2b(const float* __restrict__ io, const float* __restrict__ W2,
                        const float* __restrict__ bias, ushort_t* __restrict__ dst,
                        float* __restrict__ sums8) {
    __shared__ __align__(16) float srow[4][64];
    __shared__ float ls[4][64], lq[4][64];
    int lane = threadIdx.x & 63, wv = threadIdx.x >> 6;
    float wc[64];
#pragma unroll
    for (int h = 0; h < 64; ++h) wc[h] = W2[h * 64 + lane];
    float b = bias[lane];
    float s = 0.f, sq = 0.f;
    int wid = blockIdx.x * 4 + wv;
    int nw = gridDim.x * 4;
    for (int row = wid; row < NTOT; row += nw) {
        const float* hr = io + (size_t)row * 64;
        srow[wv][lane] = hr[lane];
        float acc = b;
#pragma unroll
        for (int h4 = 0; h4 < 16; ++h4) {
            float4 iv = *reinterpret_cast<const float4*>(&srow[wv][h4 * 4]);
            acc = fmaf(iv.x, wc[h4 * 4 + 0], acc);
            acc = fmaf(iv.y, wc[h4 * 4 + 1], acc);
            acc = fmaf(iv.z, wc[h4 * 4 + 2], acc);
            acc = fmaf(iv.w, wc[h4 * 4 + 3], acc);
        }
        acc = acc > 0.f ? acc : 0.f;
        dst[(size_t)row * 64 + lane] = f2bf(acc);
        s += acc;
        sq = fmaf(acc, acc, sq);
    }
    ls[wv][lane] = s; lq[wv][lane] = sq;
    __syncthreads();
    if (threadIdx.x < 64) {
        float S = ls[0][lane] + ls[1][lane] + ls[2][lane] + ls[3][lane];
        float Q = lq[0][lane] + lq[1][lane] + lq[2][lane] + lq[3][lane];
        float* d = sums8 + (blockIdx.x & 7) * 128;
        atomicAdd(&d[lane], S);
        atomicAdd(&d[64 + lane], Q);
    }
}

// build MFMA-layout weights: wB1f fp32 [256][192] = [wih1 | whh1] rows;
// wB2h bf16 [256][128] = [wih2 | whh2]; biases; fc1T
__global__ void k_prep(const float* __restrict__ wih1, const float* __restrict__ whh1,
                       const float* __restrict__ bih1, const float* __restrict__ bhh1,
                       const float* __restrict__ wih2, const float* __restrict__ whh2,
                       const float* __restrict__ bih2, const float* __restrict__ bhh2,
                       const float* __restrict__ fc1w,
                       float* wB1f, float* b1, ushort_t* wB2h, float* b2, float* fc1T) {
    int i = blockIdx.x * 256 + threadIdx.x;
    if (i < 256 * 192) {
        int n = i / 192, k = i - n * 192;
        wB1f[i] = (k < 128) ? wih1[n * 128 + k] : whh1[n * 64 + (k - 128)];
    }
    if (i < 256 * 128) {
        int n = i >> 7, k = i & 127;
        wB2h[i] = f2bf((k < 64) ? wih2[n * 64 + k] : whh2[n * 64 + (k - 64)]);
    }
    if (i < 208 * 64) {
        int k = i >> 6, o = i & 63;
        fc1T[i] = fc1w[o * 208 + k];
    }
    if (i < 256) { b1[i] = bih1[i] + bhh1[i]; b2[i] = bih2[i] + bhh2[i]; }
}

// fold BN2 affine into wB1f cols 64..127 + b1, then convert wB1f -> bf16
__global__ void k_fold2(float* __restrict__ wB1f, float* __restrict__ b1,
                        const float* __restrict__ ss2, ushort_t* __restrict__ wB1h) {
    int n = threadIdx.x;   // 256
    float acc = 0.f;
#pragma unroll
    for (int m = 0; m < 64; ++m) {
        float w = wB1f[n * 192 + 64 + m];
        acc = fmaf(w, ss2[64 + m], acc);
        wB1f[n * 192 + 64 + m] = w * ss2[m];
    }
    b1[n] += acc;
    __syncthreads();
    for (int j = n; j < 256 * 192; j += 256) wB1h[j] = f2bf(wB1f[j]);
}

// ---------------- MFMA 2-layer LSTM: 1 wave = 16 rows, all 10 timesteps ----------------
// mfma_f32_16x16x32_bf16. A: row=lane&15, k=(lane>>4)*8+j. B: col=lane&15, k=(lane>>4)*8+j.
// C/D: col=lane&15, row=(lane>>4)*4+q. Gates i,f,g,o of unit u live in tiles T,T+4,T+8,T+12
// at the same lane -> pointwise is lane-local. c in fp32 regs; h via swizzled LDS (bf16).
__global__ __launch_bounds__(64) void k_lstm_mfma(
    const ushort_t* __restrict__ h1bf, const ushort_t* __restrict__ h2bf,
    const ushort_t* __restrict__ wB1, const ushort_t* __restrict__ wB2,
    const float* __restrict__ bs1, const float* __restrict__ bs2,
    float* __restrict__ hA, float* __restrict__ hB) {
    __shared__ ushort_t hx1[1024], hx2[1024];   // [16 rows][64 units], 16B-granule XOR swizzle
    int lane = threadIdx.x;
    int c15 = lane & 15, g4 = lane >> 4;
    int g8 = g4 * 8;
    int bn0 = blockIdx.x * 16;                  // 16 | 10000 -> same batch for all 16 rows
    int b = bn0 / NNODES, nn0 = bn0 - b * NNODES;

    for (int i = lane; i < 512; i += 64) { ((uint_t*)hx1)[i] = 0u; ((uint_t*)hx2)[i] = 0u; }
    __syncthreads();

    float cA[16], cB[16];
#pragma unroll
    for (int s = 0; s < 16; ++s) { cA[s] = 0.f; cB[s] = 0.f; }
    float bi1[16], bi2[16];
#pragma unroll
    for (int T = 0; T < 16; ++T) { bi1[T] = bs1[T * 16 + c15]; bi2[T] = bs2[T * 16 + c15]; }

    int r7 = c15 & 7;
    int a_lo = c15 * 64 + ((g4 ^ r7) << 3);        // units 0..31 granule
    int a_hi = c15 * 64 + (((4 + g4) ^ r7) << 3);  // units 32..63 granule

    for (int t = 0; t < WINN; ++t) {
        size_t node = (size_t)((b * WINN + t) * NNODES + nn0 + c15) * 64 + g8;
        s8v a0 = *(const s8v*)(h1bf + node);
        s8v a1 = *(const s8v*)(h1bf + node + 32);
        s8v a2 = *(const s8v*)(h2bf + node);
        s8v a3 = *(const s8v*)(h2bf + node + 32);
        s8v a4 = *(const s8v*)(&hx1[a_lo]);
        s8v a5 = *(const s8v*)(&hx1[a_hi]);

        f4 acc[16];
#pragma unroll
        for (int T = 0; T < 16; ++T) { f4 v = {bi1[T], bi1[T], bi1[T], bi1[T]}; acc[T] = v; }
#pragma unroll
        for (int T = 0; T < 16; ++T) {
            const ushort_t* wc = wB1 + (size_t)(T * 16 + c15) * 192 + g8;
            acc[T] = __builtin_amdgcn_mfma_f32_16x16x32_bf16(a0, *(const s8v*)(wc), acc[T], 0, 0, 0);
            acc[T] = __builtin_amdgcn_mfma_f32_16x16x32_bf16(a1, *(const s8v*)(wc + 32), acc[T], 0, 0, 0);
            acc[T] = __builtin_amdgcn_mfma_f32_16x16x32_bf16(a2, *(const s8v*)(wc + 64), acc[T], 0, 0, 0);
            acc[T] = __builtin_amdgcn_mfma_f32_16x16x32_bf16(a3, *(const s8v*)(wc + 96), acc[T], 0, 0, 0);
            acc[T] = __builtin_amdgcn_mfma_f32_16x16x32_bf16(a4, *(const s8v*)(wc + 128), acc[T], 0, 0, 0);
            acc[T] = __builtin_amdgcn_mfma_f32_16x16x32_bf16(a5, *(const s8v*)(wc + 160), acc[T], 0, 0, 0);
        }
        __syncthreads();
        // pointwise layer 1 -> hx1
#pragma unroll
        for (int n = 0; n < 4; ++n) {
#pragma unroll
            for (int q = 0; q < 4; ++q) {
                float ig = sigmoidf_(acc[n][q]);
                float fg = sigmoidf_(acc[n + 4][q]);
                float gg = tanhf_(acc[n + 8][q]);
                float og = sigmoidf_(acc[n + 12][q]);
                int s = n * 4 + q;
                float cv = fmaf(fg, cA[s], ig * gg);
                cA[s] = cv;
                float hv = og * tanhf_(cv);
                int rr = g4 * 4 + q;
                int u = n * 16 + c15;
                hx1[rr * 64 + (((u >> 3) ^ (rr & 7)) << 3) + (u & 7)] = f2bf(hv);
            }
        }
        __syncthreads();
        // layer 2
        s8v r0 = *(const s8v*)(&hx1[a_lo]);
        s8v r1 = *(const s8v*)(&hx1[a_hi]);
        s8v r2 = *(const s8v*)(&hx2[a_lo]);
        s8v r3 = *(const s8v*)(&hx2[a_hi]);
#pragma unroll
        for (int T = 0; T < 16; ++T) { f4 v = {bi2[T], bi2[T], bi2[T], bi2[T]}; acc[T] = v; }
#pragma unroll
        for (int T = 0; T < 16; ++T) {
            const ushort_t* wc = wB2 + (size_t)(T * 16 + c15) * 128 + g8;
            acc[T] = __builtin_amdgcn_mfma_f32_16x16x32_bf16(r0, *(const s8v*)(wc), acc[T], 0, 0, 0);
            acc[T] = __builtin_amdgcn_mfma_f32_16x16x32_bf16(r1, *(const s8v*)(wc + 32), acc[T], 0, 0, 0);
            acc[T] = __builtin_amdgcn_mfma_f32_16x16x32_bf16(r2, *(const s8v*)(wc + 64), acc[T], 0, 0, 0);
            acc[T] = __builtin_amdgcn_mfma_f32_16x16x32_bf16(r3, *(const s8v*)(wc + 96), acc[T], 0, 0, 0);
        }
        __syncthreads();
        // pointwise layer 2 -> hx2
#pragma unroll
        for (int n = 0; n < 4; ++n) {
#pragma unroll
            for (int q = 0; q < 4; ++q) {
                float ig = sigmoidf_(acc[n][q]);
                float fg = sigmoidf_(acc[n + 4][q]);
                float gg = tanhf_(acc[n + 8][q]);
                float og = sigmoidf_(acc[n + 12][q]);
                int s = n * 4 + q;
                float cv = fmaf(fg, cB[s], ig * gg);
                cB[s] = cv;
                float hv = og * tanhf_(cv);
                int rr = g4 * 4 + q;
                int u = n * 16 + c15;
                hx2[rr * 64 + (((u >> 3) ^ (rr & 7)) << 3) + (u & 7)] = f2bf(hv);
            }
        }
        __syncthreads();
    }
    // final hidden states -> global fp32
    for (int i = lane; i < 1024; i += 64) {
        int rr = i >> 6, u = i & 63;
        int hw = rr * 64 + (((u >> 3) ^ (rr & 7)) << 3) + (u & 7);
        hA[(size_t)(bn0 + rr) * 64 + u] = bf2f(hx1[hw]);
        hB[(size_t)(bn0 + rr) * 64 + u] = bf2f(hx2[hw]);
    }
}

// head: z = relu([hn1|hn2|skip] @ fc1^T + b1); out = relu(z @ fc2^T + b2)
__global__ void k_head(const float* __restrict__ hA, const float* __restrict__ hB,
                       const float* __restrict__ x, const float* __restrict__ fc1T,
                       const float* __restrict__ fc1b, const float* __restrict__ fc2w,
                       const float* __restrict__ fc2b, float* __restrict__ out) {
    int lane = threadIdx.x & 63, wv = threadIdx.x >> 6;
    int bn = blockIdx.x * 4 + wv;
    __shared__ float sz[4][208];
    int b = bn / NNODES, nn = bn - b * NNODES;
    for (int k = lane; k < 208; k += 64) {
        float v;
        if (k < 64) v = hA[(size_t)bn * 64 + k];
        else if (k < 128) v = hB[(size_t)bn * 64 + (k - 64)];
        else {
            int kk = k - 128;
            int w = kk >> 3, f = kk & 7;
            v = x[(size_t)((b * WINN + w) * NNODES + nn) * NFEAT + f];
        }
        sz[wv][k] = v;
    }
    __syncthreads();
    float acc = fc1b[lane];
    for (int k = 0; k < 208; ++k) acc = fmaf(sz[wv][k], fc1T[k * 64 + lane], acc);
    acc = acc > 0.f ? acc : 0.f;
    float v = acc * fc2w[lane];
#pragma unroll
    for (int m = 32; m >= 1; m >>= 1) v += __shfl_xor(v, m, 64);
    if (lane == 0) {
        float z = v + fc2b[0];
        out[bn] = z > 0.f ? z : 0.f;
    }
}

// ---------------- launch ----------------
extern "C" void kernel_launch(void* const* d_in, const int* in_sizes, int n_in,
                              void* d_out, int out_size, void* d_ws, size_t ws_size,
                              hipStream_t stream) {
    const float* x     = (const float*)d_in[0];
    const int*   ei    = (const int*)d_in[1];
    const float* ew    = (const float*)d_in[2];
    const float* c1w   = (const float*)d_in[3];
    const float* c1b   = (const float*)d_in[4];
    const float* c2w   = (const float*)d_in[5];
    const float* c2b   = (const float*)d_in[6];
    const float* bn1g  = (const float*)d_in[7];
    const float* bn1b  = (const float*)d_in[8];
    const float* bn2g  = (const float*)d_in[9];
    const float* bn2b  = (const float*)d_in[10];
    const float* wih1  = (const float*)d_in[11];
    const float* whh1  = (const float*)d_in[12];
    const float* bih1  = (const float*)d_in[13];
    const float* bhh1  = (const float*)d_in[14];
    const float* wih2  = (const float*)d_in[15];
    const float* whh2  = (const float*)d_in[16];
    const float* bih2  = (const float*)d_in[17];
    const float* bhh2  = (const float*)d_in[18];
    const float* fc1w  = (const float*)d_in[19];
    const float* fc1b  = (const float*)d_in[20];
    const float* fc2w  = (const float*)d_in[21];
    const float* fc2b  = (const float*)d_in[22];
    float* out = (float*)d_out;

    float* ws = (float*)d_ws;
    size_t off = 0;
    auto A = [&](size_t n) { float* p = ws + off; off += n; return p; };
    float* dinv   = A(NTOT);
    float* aggX   = A((size_t)NTOT * NFEAT);
    float* big    = A((size_t)NTOT * 64);       // preH1 (layer1), then agg2 (layer2)
    ushort_t* h1bf = (ushort_t*)A((size_t)NTOT * 32);   // NTOT*64 bf16
    ushort_t* h2bf = (ushort_t*)A((size_t)NTOT * 32);

    // union: CSR (GCN phase) aliases final LSTM states (LSTM/head phase)
    size_t uoff = off;
    float* hA = A((size_t)NBN * 64);
    float* hB = A((size_t)NBN * 64);
    A(2 * (size_t)NEDGE + 2 * NTOT + 2 - 2 * (size_t)NBN * 64);  // extend to CSR size
    int2* epack = (int2*)(ws + uoff);
    int*  ptr   = (int*)(epack + NEDGE);
    int*  cur   = ptr + NTOT + 1;

    float* wB1f = A(256 * 192);
    ushort_t* wB1h = (ushort_t*)A(256 * 96);    // 256*192 bf16
    ushort_t* wB2h = (ushort_t*)A(256 * 64);    // 256*128 bf16
    float* b1   = A(256);
    float* b2   = A(256);
    float* fc1T = A(208 * 64);
    float* sums = A(2048);
    float* ss1  = A(128);
    float* ss2  = A(128);
    float* scanTmpF = A(512);
    int* scanTmp = (int*)scanTmpF;
    // total ~62.2M floats = 237 MB < 256 MiB

    if (ws_size < off * sizeof(float)) {
        k_diag<<<(out_size + 255) / 256, 256, 0, stream>>>(out, (float)ws_size, out_size);
        return;
    }

    constexpr int SCAN_NB = (NTOT + 1023) / 1024;

    k_init<<<(NTOT + 255) / 256, 256, 0, stream>>>(dinv, cur, sums);
    k_deg<<<NEDGE / 256, 256, 0, stream>>>(ei, ew, dinv, cur);
    k_dinv<<<(NTOT + 255) / 256, 256, 0, stream>>>(dinv);
    k_scan1<<<SCAN_NB, 256, 0, stream>>>(cur, ptr, scanTmp);
    k_scan2<<<1, 512, 0, stream>>>(scanTmp, SCAN_NB);
    k_scan3<<<(NTOT + 255) / 256, 256, 0, stream>>>(ptr, cur, scanTmp);
    k_fill<<<NEDGE / 256, 256, 0, stream>>>(ei, ew, dinv, cur, epack);
    k_prep<<<192, 256, 0, stream>>>(wih1, whh1, bih1, bhh1, wih2, whh2, bih2, bhh2,
                                    fc1w, wB1f, b1, wB2h, b2, fc1T);

    // ---- GCN layer 1 ----
    k_gather8<<<NTOT / 8 / 4, 256, 0, stream>>>(ptr, epack, x, dinv, aggX);
    k_lin1<<<512, 256, 0, stream>>>(aggX, c1w, c1b, big, sums);
    k_bn_final<<<1, 64, 0, stream>>>(sums, bn1g, bn1b, ss1);
    k_bn1cast<<<2048, 256, 0, stream>>>(big, ss1, h1bf);    // big(preH1) -> h1bf

    // ---- GCN layer 2 ----
    k_gather64<<<NTOT / 4, 256, 0, stream>>>(ptr, epack, h1bf, dinv, big);  // big := agg2
    k_lin2b<<<2048, 256, 0, stream>>>(big, c2w, c2b, h2bf, sums + 128);
    k_bn_final8<<<1, 64, 0, stream>>>(sums + 128, bn2g, bn2b, ss2);
    k_fold2<<<1, 256, 0, stream>>>(wB1f, b1, ss2, wB1h);

    // ---- MFMA LSTM (CSR region dead; writes hA/hB into union) ----
    k_lstm_mfma<<<NBN / 16, 64, 0, stream>>>(h1bf, h2bf, wB1h, wB2h, b1, b2, hA, hB);

    // ---- head ----
    k_head<<<NBN / 4, 256, 0, stream>>>(hA, hB, x, fc1T, fc1b, fc2w, fc2b, out);
}

// Round 8
// 1216.941 us; speedup vs baseline: 4.7778x; 1.8726x over previous
//
#include <hip/hip_runtime.h>
#include <math.h>

// ---------------- problem constants ----------------
constexpr int BB     = 4;
constexpr int WINN   = 10;
constexpr int NNODES = 10000;
constexpr int NFEAT  = 8;
constexpr int NHID   = 64;
constexpr int NTOT   = BB * WINN * NNODES;   // 400000 stacked nodes
constexpr int NEDGE  = 3200000;
constexpr int NBN    = BB * NNODES;          // 40000 sequences
constexpr float EPSBN = 1e-5f;

#define DEVFN static __device__ __forceinline__

typedef float f4 __attribute__((ext_vector_type(4)));
typedef short s8v __attribute__((ext_vector_type(8)));
typedef unsigned short ushort_t;
typedef unsigned int uint_t;

DEVFN float sigmoidf_(float x) { return 1.0f / (1.0f + __expf(-x)); }
DEVFN float tanhf_(float x) { return 2.0f / (1.0f + __expf(-2.0f * x)) - 1.0f; }
DEVFN ushort_t f2bf(float f) {             // round-to-nearest-even bf16
    uint_t x = __float_as_uint(f);
    return (ushort_t)((x + 0x7FFFu + ((x >> 16) & 1u)) >> 16);
}
DEVFN float bf2f(ushort_t u) { return __uint_as_float(((uint_t)u) << 16); }

// ---------------- diagnostic ----------------
__global__ void k_diag(float* out, float wsz, int n) {
    int i = blockIdx.x * 256 + threadIdx.x;
    if (i < n) out[i] = wsz;
}

// ---------------- init ----------------
__global__ void k_init(float* deg, int* cnt, float* sums) {
    int i = blockIdx.x * 256 + threadIdx.x;
    if (i < NTOT) { deg[i] = 1.0f; cnt[i] = 0; }
    if (i < 2048) sums[i] = 0.f;
}

__global__ void k_deg(const int* __restrict__ ei, const float* __restrict__ ew,
                      float* deg, int* cnt) {
    int e = blockIdx.x * 256 + threadIdx.x;
    if (e < NEDGE) {
        int c = ei[NEDGE + e];
        atomicAdd(&deg[c], ew[e]);
        atomicAdd(&cnt[c], 1);
    }
}

__global__ void k_dinv(float* deg) {
    int i = blockIdx.x * 256 + threadIdx.x;
    if (i < NTOT) { float d = deg[i]; deg[i] = (d > 0.f) ? rsqrtf(d) : 0.f; }
}

// ---------------- scan ----------------
__global__ void k_scan1(const int* __restrict__ cnt, int* __restrict__ ptr, int* __restrict__ tmp) {
    __shared__ int sdat[256];
    int tid = threadIdx.x;
    int base = blockIdx.x * 1024 + tid * 4;
    int v0 = (base + 0 < NTOT) ? cnt[base + 0] : 0;
    int v1 = (base + 1 < NTOT) ? cnt[base + 1] : 0;
    int v2 = (base + 2 < NTOT) ? cnt[base + 2] : 0;
    int v3 = (base + 3 < NTOT) ? cnt[base + 3] : 0;
    int sum = v0 + v1 + v2 + v3;
    sdat[tid] = sum;
    __syncthreads();
    for (int ofs = 1; ofs < 256; ofs <<= 1) {
        int x = (tid >= ofs) ? sdat[tid - ofs] : 0;
        __syncthreads();
        sdat[tid] += x;
        __syncthreads();
    }
    int run = sdat[tid] - sum;
    if (base + 0 < NTOT) ptr[base + 0] = run; run += v0;
    if (base + 1 < NTOT) ptr[base + 1] = run; run += v1;
    if (base + 2 < NTOT) ptr[base + 2] = run; run += v2;
    if (base + 3 < NTOT) ptr[base + 3] = run;
    if (tid == 255) tmp[blockIdx.x] = sdat[255];
}

__global__ void k_scan2(int* tmp, int nb) {
    __shared__ int st[512];
    int tid = threadIdx.x;
    int v = (tid < nb) ? tmp[tid] : 0;
    st[tid] = v;
    __syncthreads();
    for (int ofs = 1; ofs < 512; ofs <<= 1) {
        int x = (tid >= ofs) ? st[tid - ofs] : 0;
        __syncthreads();
        st[tid] += x;
        __syncthreads();
    }
    if (tid < nb) tmp[tid] = st[tid] - v;
}

__global__ void k_scan3(int* __restrict__ ptr, int* __restrict__ cur, const int* __restrict__ tmp) {
    int i = blockIdx.x * 256 + threadIdx.x;
    if (i < NTOT) {
        int p = ptr[i] + tmp[i >> 10];
        ptr[i] = p;
        cur[i] = p;
    }
    if (i == 0) ptr[NTOT] = NEDGE;
}

__global__ void k_fill(const int* __restrict__ ei, const float* __restrict__ ew,
                       const float* __restrict__ dinv, int* __restrict__ cur,
                       int2* __restrict__ epack) {
    int e = blockIdx.x * 256 + threadIdx.x;
    if (e >= NEDGE) return;
    int row = ei[e], col = ei[NEDGE + e];
    float nv = dinv[row] * ew[e] * dinv[col];
    int pos = atomicAdd(&cur[col], 1);
    epack[pos] = make_int2(row, __float_as_int(nv));
}

// layer-1 gather over raw features (8 ch)
__global__ void k_gather8(const int* __restrict__ ptr, const int2* __restrict__ epack,
                          const float* __restrict__ x, const float* __restrict__ dinv,
                          float* __restrict__ aggX) {
    int tid = threadIdx.x;
    int lane = tid & 63;
    int waveg = blockIdx.x * 4 + (tid >> 6);
    int g = lane >> 3, ch = lane & 7;
    int node = waveg * 8 + g;
    int beg = ptr[node], end = ptr[node + 1];
    float dv = dinv[node];
    float acc = dv * dv * x[node * 8 + ch];
    int e = beg;
    for (; e + 1 < end; e += 2) {
        int2 p0 = epack[e], p1 = epack[e + 1];
        acc = fmaf(__int_as_float(p0.y), x[p0.x * 8 + ch], acc);
        acc = fmaf(__int_as_float(p1.y), x[p1.x * 8 + ch], acc);
    }
    if (e < end) {
        int2 p = epack[e];
        acc = fmaf(__int_as_float(p.y), x[p.x * 8 + ch], acc);
    }
    aggX[node * 8 + ch] = acc;
}

// layer-2 gather (64 ch) from bf16 h1, self-loop folded
__global__ void k_gather64(const int* __restrict__ ptr, const int2* __restrict__ epack,
                           const ushort_t* __restrict__ src, const float* __restrict__ dinv,
                           float* __restrict__ dst) {
    int lane = threadIdx.x & 63;
    int node = blockIdx.x * 4 + (threadIdx.x >> 6);
    int beg = ptr[node], end = ptr[node + 1];
    float dv = dinv[node];
    float acc = dv * dv * bf2f(src[(size_t)node * 64 + lane]);
    int e = beg;
    for (; e + 1 < end; e += 2) {
        int2 p0 = epack[e], p1 = epack[e + 1];
        acc = fmaf(__int_as_float(p0.y), bf2f(src[(size_t)p0.x * 64 + lane]), acc);
        acc = fmaf(__int_as_float(p1.y), bf2f(src[(size_t)p1.x * 64 + lane]), acc);
    }
    if (e < end) {
        int2 p = epack[e];
        acc = fmaf(__int_as_float(p.y), bf2f(src[(size_t)p.x * 64 + lane]), acc);
    }
    dst[(size_t)node * 64 + lane] = acc;
}

// preH1 = relu(aggX @ W1 + b) + BN stats
__global__ void k_lin1(const float* __restrict__ aggX, const float* __restrict__ W,
                       const float* __restrict__ bias, float* __restrict__ h1,
                       float* __restrict__ sums) {
    __shared__ float sW[NFEAT * NHID];
    int tid = threadIdx.x;
    sW[tid] = W[tid];
    sW[tid + 256] = W[tid + 256];
    __syncthreads();
    int c = tid & 63;
    float b = bias[c];
    float s = 0.f, sq = 0.f;
    int stride = gridDim.x * 256;
    for (int i = blockIdx.x * 256 + tid; i < NTOT * 64; i += stride) {
        int n = i >> 6;
        float acc = b;
#pragma unroll
        for (int f = 0; f < NFEAT; ++f) acc = fmaf(aggX[n * NFEAT + f], sW[f * NHID + c], acc);
        acc = acc > 0.f ? acc : 0.f;
        h1[i] = acc;
        s += acc;
        sq = fmaf(acc, acc, sq);
    }
    __shared__ float ls[4][64], lq[4][64];
    int w = tid >> 6;
    ls[w][c] = s; lq[w][c] = sq;
    __syncthreads();
    if (tid < 64) {
        atomicAdd(&sums[tid], ls[0][tid] + ls[1][tid] + ls[2][tid] + ls[3][tid]);
        atomicAdd(&sums[64 + tid], lq[0][tid] + lq[1][tid] + lq[2][tid] + lq[3][tid]);
    }
}

__global__ void k_bn_final(const float* __restrict__ sums, const float* __restrict__ g,
                           const float* __restrict__ b, float* __restrict__ ss) {
    int i = threadIdx.x;
    if (i >= 64) return;
    float mean = sums[i] * (1.0f / NTOT);
    float var = sums[64 + i] * (1.0f / NTOT) - mean * mean;
    float sc = g[i] * rsqrtf(var + EPSBN);
    ss[i] = sc;
    ss[64 + i] = b[i] - mean * sc;
}

__global__ void k_bn_final8(const float* __restrict__ sums8, const float* __restrict__ g,
                            const float* __restrict__ b, float* __restrict__ ss) {
    int i = threadIdx.x;
    if (i >= 64) return;
    float S = 0.f, Q = 0.f;
#pragma unroll
    for (int m = 0; m < 8; ++m) { S += sums8[m * 128 + i]; Q += sums8[m * 128 + 64 + i]; }
    float mean = S * (1.0f / NTOT);
    float var = Q * (1.0f / NTOT) - mean * mean;
    float sc = g[i] * rsqrtf(var + EPSBN);
    ss[i] = sc;
    ss[64 + i] = b[i] - mean * sc;
}

// h1bf = bf16(preH1*sc + sh)   (BN1 apply + cast)
__global__ void k_bn1cast(const float* __restrict__ pre, const float* __restrict__ ss,
                          ushort_t* __restrict__ dst) {
    int c = threadIdx.x & 63;
    float sc = ss[c], sh = ss[64 + c];
    int stride = gridDim.x * 256;
    for (int i = blockIdx.x * 256 + threadIdx.x; i < NTOT * 64; i += stride)
        dst[i] = f2bf(fmaf(pre[i], sc, sh));
}

// h2bf = bf16(relu(row @ W2 + b)) + BN stats (pre-BN; BN2 folded into LSTM weights)
__global__ void k_lin2b(const float* __restrict__ io, const float* __restrict__ W2,
                        const float* __restrict__ bias, ushort_t* __restrict__ dst,
                        float* __restrict__ sums8) {
    __shared__ __align__(16) float srow[4][64];
    __shared__ float ls[4][64], lq[4][64];
    int lane = threadIdx.x & 63, wv = threadIdx.x >> 6;
    float wc[64];
#pragma unroll
    for (int h = 0; h < 64; ++h) wc[h] = W2[h * 64 + lane];
    float b = bias[lane];
    float s = 0.f, sq = 0.f;
    int wid = blockIdx.x * 4 + wv;
    int nw = gridDim.x * 4;
    for (int row = wid; row < NTOT; row += nw) {
        const float* hr = io + (size_t)row * 64;
        srow[wv][lane] = hr[lane];
        float acc = b;
#pragma unroll
        for (int h4 = 0; h4 < 16; ++h4) {
            float4 iv = *reinterpret_cast<const float4*>(&srow[wv][h4 * 4]);
            acc = fmaf(iv.x, wc[h4 * 4 + 0], acc);
            acc = fmaf(iv.y, wc[h4 * 4 + 1], acc);
            acc = fmaf(iv.z, wc[h4 * 4 + 2], acc);
            acc = fmaf(iv.w, wc[h4 * 4 + 3], acc);
        }
        acc = acc > 0.f ? acc : 0.f;
        dst[(size_t)row * 64 + lane] = f2bf(acc);
        s += acc;
        sq = fmaf(acc, acc, sq);
    }
    ls[wv][lane] = s; lq[wv][lane] = sq;
    __syncthreads();
    if (threadIdx.x < 64) {
        float S = ls[0][lane] + ls[1][lane] + ls[2][lane] + ls[3][lane];
        float Q = lq[0][lane] + lq[1][lane] + lq[2][lane] + lq[3][lane];
        float* d = sums8 + (blockIdx.x & 7) * 128;
        atomicAdd(&d[lane], S);
        atomicAdd(&d[64 + lane], Q);
    }
}

// build MFMA-layout weights: wB1f fp32 [256][192]; wB2h bf16 [256][128]; biases; fc1T
__global__ void k_prep(const float* __restrict__ wih1, const float* __restrict__ whh1,
                       const float* __restrict__ bih1, const float* __restrict__ bhh1,
                       const float* __restrict__ wih2, const float* __restrict__ whh2,
                       const float* __restrict__ bih2, const float* __restrict__ bhh2,
                       const float* __restrict__ fc1w,
                       float* wB1f, float* b1, ushort_t* wB2h, float* b2, float* fc1T) {
    int i = blockIdx.x * 256 + threadIdx.x;
    if (i < 256 * 192) {
        int n = i / 192, k = i - n * 192;
        wB1f[i] = (k < 128) ? wih1[n * 128 + k] : whh1[n * 64 + (k - 128)];
    }
    if (i < 256 * 128) {
        int n = i >> 7, k = i & 127;
        wB2h[i] = f2bf((k < 64) ? wih2[n * 64 + k] : whh2[n * 64 + (k - 64)]);
    }
    if (i < 208 * 64) {
        int k = i >> 6, o = i & 63;
        fc1T[i] = fc1w[o * 208 + k];
    }
    if (i < 256) { b1[i] = bih1[i] + bhh1[i]; b2[i] = bih2[i] + bhh2[i]; }
}

// fold BN2 affine into wB1f cols 64..127 + b1, then convert wB1f -> bf16
__global__ void k_fold2(float* __restrict__ wB1f, float* __restrict__ b1,
                        const float* __restrict__ ss2, ushort_t* __restrict__ wB1h) {
    int n = threadIdx.x;   // 256
    float acc = 0.f;
#pragma unroll
    for (int m = 0; m < 64; ++m) {
        float w = wB1f[n * 192 + 64 + m];
        acc = fmaf(w, ss2[64 + m], acc);
        wB1f[n * 192 + 64 + m] = w * ss2[m];
    }
    b1[n] += acc;
    __syncthreads();
    for (int j = n; j < 256 * 192; j += 256) wB1h[j] = f2bf(wB1f[j]);
}

// ---------------- MFMA 2-layer LSTM: 4 waves/block, 16 rows, weights in registers ----
// Wave wv owns units wv*16..wv*16+15 (tiles wv, wv+4, wv+8, wv+12 = gates i,f,g,o);
// its 40 KB weight slice is loaded into VGPRs ONCE and held for all 10 timesteps.
// A: row=lane&15, k=(lane>>4)*8+j. C/D: col=lane&15, row=(lane>>4)*4+q.
// h-state exchange via XOR-swizzled 2KB LDS buffers; c stays fp32 in registers.
__global__ __launch_bounds__(256, 2) void k_lstm_mfma4(
    const ushort_t* __restrict__ h1bf, const ushort_t* __restrict__ h2bf,
    const ushort_t* __restrict__ wB1, const ushort_t* __restrict__ wB2,
    const float* __restrict__ bs1, const float* __restrict__ bs2,
    float* __restrict__ hA, float* __restrict__ hB) {
    __shared__ ushort_t hx1[1024], hx2[1024];   // [16 rows][64 units], 16B-granule XOR swizzle
    int tid = threadIdx.x;
    int lane = tid & 63, wv = tid >> 6;
    int c15 = lane & 15, g4 = lane >> 4;
    int g8 = g4 * 8;
    int bn0 = blockIdx.x * 16;                  // 16 | 10000 -> same batch for all 16 rows
    int b = bn0 / NNODES, nn0 = bn0 - b * NNODES;

    for (int i = tid; i < 512; i += 256) { ((uint_t*)hx1)[i] = 0u; ((uint_t*)hx2)[i] = 0u; }

    // persistent per-wave weight fragments (static indexing -> VGPRs)
    s8v w1f[4][6], w2f[4][4];
#pragma unroll
    for (int j = 0; j < 4; ++j) {
        const ushort_t* base1 = wB1 + (size_t)((wv + 4 * j) * 16 + c15) * 192 + g8;
#pragma unroll
        for (int kk = 0; kk < 6; ++kk) w1f[j][kk] = *(const s8v*)(base1 + kk * 32);
        const ushort_t* base2 = wB2 + (size_t)((wv + 4 * j) * 16 + c15) * 128 + g8;
#pragma unroll
        for (int kk = 0; kk < 4; ++kk) w2f[j][kk] = *(const s8v*)(base2 + kk * 32);
    }
    float bi1[4], bi2[4];
#pragma unroll
    for (int j = 0; j < 4; ++j) {
        bi1[j] = bs1[(wv + 4 * j) * 16 + c15];
        bi2[j] = bs2[(wv + 4 * j) * 16 + c15];
    }
    float cA[4], cB[4];
#pragma unroll
    for (int q = 0; q < 4; ++q) { cA[q] = 0.f; cB[q] = 0.f; }

    int r7 = c15 & 7;
    int a_lo = c15 * 64 + ((g4 ^ r7) << 3);        // units 0..31 granule
    int a_hi = c15 * 64 + (((4 + g4) ^ r7) << 3);  // units 32..63 granule
    int u = wv * 16 + c15;                          // this wave's unit for lane
    int hxcol_hi = (u >> 3) << 3;                   // granule base of u (pre-XOR)
    int u7 = u & 7;

    __syncthreads();

    for (int t = 0; t < WINN; ++t) {
        size_t node = (size_t)((b * WINN + t) * NNODES + nn0 + c15) * 64 + g8;
        s8v a[6];
        a[0] = *(const s8v*)(h1bf + node);
        a[1] = *(const s8v*)(h1bf + node + 32);
        a[2] = *(const s8v*)(h2bf + node);
        a[3] = *(const s8v*)(h2bf + node + 32);
        a[4] = *(const s8v*)(&hx1[a_lo]);
        a[5] = *(const s8v*)(&hx1[a_hi]);

        f4 acc[4];
#pragma unroll
        for (int j = 0; j < 4; ++j) { f4 v = {bi1[j], bi1[j], bi1[j], bi1[j]}; acc[j] = v; }
#pragma unroll
        for (int j = 0; j < 4; ++j)
#pragma unroll
            for (int kk = 0; kk < 6; ++kk)
                acc[j] = __builtin_amdgcn_mfma_f32_16x16x32_bf16(a[kk], w1f[j][kk], acc[j], 0, 0, 0);
        __syncthreads();   // all waves done reading hx1(prev)
        // pointwise layer 1 -> hx1(new)
#pragma unroll
        for (int q = 0; q < 4; ++q) {
            float ig = sigmoidf_(acc[0][q]);
            float fg = sigmoidf_(acc[1][q]);
            float gg = tanhf_(acc[2][q]);
            float og = sigmoidf_(acc[3][q]);
            float cv = fmaf(fg, cA[q], ig * gg);
            cA[q] = cv;
            float hv = og * tanhf_(cv);
            int rr = g4 * 4 + q;
            hx1[rr * 64 + (hxcol_hi ^ ((rr & 7) << 3)) + u7] = f2bf(hv);
        }
        __syncthreads();   // hx1(new) visible

        s8v r[4];
        r[0] = *(const s8v*)(&hx1[a_lo]);
        r[1] = *(const s8v*)(&hx1[a_hi]);
        r[2] = *(const s8v*)(&hx2[a_lo]);
        r[3] = *(const s8v*)(&hx2[a_hi]);
#pragma unroll
        for (int j = 0; j < 4; ++j) { f4 v = {bi2[j], bi2[j], bi2[j], bi2[j]}; acc[j] = v; }
#pragma unroll
        for (int j = 0; j < 4; ++j)
#pragma unroll
            for (int kk = 0; kk < 4; ++kk)
                acc[j] = __builtin_amdgcn_mfma_f32_16x16x32_bf16(r[kk], w2f[j][kk], acc[j], 0, 0, 0);
        __syncthreads();   // all waves done reading hx2(prev)
        // pointwise layer 2 -> hx2(new)
#pragma unroll
        for (int q = 0; q < 4; ++q) {
            float ig = sigmoidf_(acc[0][q]);
            float fg = sigmoidf_(acc[1][q]);
            float gg = tanhf_(acc[2][q]);
            float og = sigmoidf_(acc[3][q]);
            float cv = fmaf(fg, cB[q], ig * gg);
            cB[q] = cv;
            float hv = og * tanhf_(cv);
            int rr = g4 * 4 + q;
            hx2[rr * 64 + (hxcol_hi ^ ((rr & 7) << 3)) + u7] = f2bf(hv);
        }
        __syncthreads();   // hx2(new) visible
    }
    // final hidden states -> global fp32
    for (int i = tid; i < 1024; i += 256) {
        int rr = i >> 6, uu = i & 63;
        int hw = rr * 64 + ((((uu >> 3) ^ (rr & 7)) << 3)) + (uu & 7);
        hA[(size_t)(bn0 + rr) * 64 + uu] = bf2f(hx1[hw]);
        hB[(size_t)(bn0 + rr) * 64 + uu] = bf2f(hx2[hw]);
    }
}

// head: z = relu([hn1|hn2|skip] @ fc1^T + b1); out = relu(z @ fc2^T + b2)
__global__ void k_head(const float* __restrict__ hA, const float* __restrict__ hB,
                       const float* __restrict__ x, const float* __restrict__ fc1T,
                       const float* __restrict__ fc1b, const float* __restrict__ fc2w,
                       const float* __restrict__ fc2b, float* __restrict__ out) {
    int lane = threadIdx.x & 63, wv = threadIdx.x >> 6;
    int bn = blockIdx.x * 4 + wv;
    __shared__ float sz[4][208];
    int b = bn / NNODES, nn = bn - b * NNODES;
    for (int k = lane; k < 208; k += 64) {
        float v;
        if (k < 64) v = hA[(size_t)bn * 64 + k];
        else if (k < 128) v = hB[(size_t)bn * 64 + (k - 64)];
        else {
            int kk = k - 128;
            int w = kk >> 3, f = kk & 7;
            v = x[(size_t)((b * WINN + w) * NNODES + nn) * NFEAT + f];
        }
        sz[wv][k] = v;
    }
    __syncthreads();
    float acc = fc1b[lane];
    for (int k = 0; k < 208; ++k) acc = fmaf(sz[wv][k], fc1T[k * 64 + lane], acc);
    acc = acc > 0.f ? acc : 0.f;
    float v = acc * fc2w[lane];
#pragma unroll
    for (int m = 32; m >= 1; m >>= 1) v += __shfl_xor(v, m, 64);
    if (lane == 0) {
        float z = v + fc2b[0];
        out[bn] = z > 0.f ? z : 0.f;
    }
}

// ---------------- launch ----------------
extern "C" void kernel_launch(void* const* d_in, const int* in_sizes, int n_in,
                              void* d_out, int out_size, void* d_ws, size_t ws_size,
                              hipStream_t stream) {
    const float* x     = (const float*)d_in[0];
    const int*   ei    = (const int*)d_in[1];
    const float* ew    = (const float*)d_in[2];
    const float* c1w   = (const float*)d_in[3];
    const float* c1b   = (const float*)d_in[4];
    const float* c2w   = (const float*)d_in[5];
    const float* c2b   = (const float*)d_in[6];
    const float* bn1g  = (const float*)d_in[7];
    const float* bn1b  = (const float*)d_in[8];
    const float* bn2g  = (const float*)d_in[9];
    const float* bn2b  = (const float*)d_in[10];
    const float* wih1  = (const float*)d_in[11];
    const float* whh1  = (const float*)d_in[12];
    const float* bih1  = (const float*)d_in[13];
    const float* bhh1  = (const float*)d_in[14];
    const float* wih2  = (const float*)d_in[15];
    const float* whh2  = (const float*)d_in[16];
    const float* bih2  = (const float*)d_in[17];
    const float* bhh2  = (const float*)d_in[18];
    const float* fc1w  = (const float*)d_in[19];
    const float* fc1b  = (const float*)d_in[20];
    const float* fc2w  = (const float*)d_in[21];
    const float* fc2b  = (const float*)d_in[22];
    float* out = (float*)d_out;

    float* ws = (float*)d_ws;
    size_t off = 0;
    auto A = [&](size_t n) { float* p = ws + off; off += n; return p; };
    float* dinv   = A(NTOT);
    float* aggX   = A((size_t)NTOT * NFEAT);
    float* big    = A((size_t)NTOT * 64);       // preH1 (layer1), then agg2 (layer2)
    ushort_t* h1bf = (ushort_t*)A((size_t)NTOT * 32);   // NTOT*64 bf16
    ushort_t* h2bf = (ushort_t*)A((size_t)NTOT * 32);

    // union: CSR (GCN phase) aliases final LSTM states (LSTM/head phase)
    size_t uoff = off;
    float* hA = A((size_t)NBN * 64);
    float* hB = A((size_t)NBN * 64);
    A(2 * (size_t)NEDGE + 2 * NTOT + 2 - 2 * (size_t)NBN * 64);  // extend to CSR size
    int2* epack = (int2*)(ws + uoff);
    int*  ptr   = (int*)(epack + NEDGE);
    int*  cur   = ptr + NTOT + 1;

    float* wB1f = A(256 * 192);
    ushort_t* wB1h = (ushort_t*)A(256 * 96);    // 256*192 bf16
    ushort_t* wB2h = (ushort_t*)A(256 * 64);    // 256*128 bf16
    float* b1   = A(256);
    float* b2   = A(256);
    float* fc1T = A(208 * 64);
    float* sums = A(2048);
    float* ss1  = A(128);
    float* ss2  = A(128);
    float* scanTmpF = A(512);
    int* scanTmp = (int*)scanTmpF;
    // total ~62.2M floats = 237 MB < 256 MiB

    if (ws_size < off * sizeof(float)) {
        k_diag<<<(out_size + 255) / 256, 256, 0, stream>>>(out, (float)ws_size, out_size);
        return;
    }

    constexpr int SCAN_NB = (NTOT + 1023) / 1024;

    k_init<<<(NTOT + 255) / 256, 256, 0, stream>>>(dinv, cur, sums);
    k_deg<<<NEDGE / 256, 256, 0, stream>>>(ei, ew, dinv, cur);
    k_dinv<<<(NTOT + 255) / 256, 256, 0, stream>>>(dinv);
    k_scan1<<<SCAN_NB, 256, 0, stream>>>(cur, ptr, scanTmp);
    k_scan2<<<1, 512, 0, stream>>>(scanTmp, SCAN_NB);
    k_scan3<<<(NTOT + 255) / 256, 256, 0, stream>>>(ptr, cur, scanTmp);
    k_fill<<<NEDGE / 256, 256, 0, stream>>>(ei, ew, dinv, cur, epack);
    k_prep<<<192, 256, 0, stream>>>(wih1, whh1, bih1, bhh1, wih2, whh2, bih2, bhh2,
                                    fc1w, wB1f, b1, wB2h, b2, fc1T);

    // ---- GCN layer 1 ----
    k_gather8<<<NTOT / 8 / 4, 256, 0, stream>>>(ptr, epack, x, dinv, aggX);
    k_lin1<<<512, 256, 0, stream>>>(aggX, c1w, c1b, big, sums);
    k_bn_final<<<1, 64, 0, stream>>>(sums, bn1g, bn1b, ss1);
    k_bn1cast<<<2048, 256, 0, stream>>>(big, ss1, h1bf);    // big(preH1) -> h1bf

    // ---- GCN layer 2 ----
    k_gather64<<<NTOT / 4, 256, 0, stream>>>(ptr, epack, h1bf, dinv, big);  // big := agg2
    k_lin2b<<<2048, 256, 0, stream>>>(big, c2w, c2b, h2bf, sums + 128);
    k_bn_final8<<<1, 64, 0, stream>>>(sums + 128, bn2g, bn2b, ss2);
    k_fold2<<<1, 256, 0, stream>>>(wB1f, b1, ss2, wB1h);

    // ---- MFMA LSTM: 4 waves/block, weights resident in VGPRs ----
    k_lstm_mfma4<<<NBN / 16, 256, 0, stream>>>(h1bf, h2bf, wB1h, wB2h, b1, b2, hA, hB);

    // ---- head ----
    k_head<<<NBN / 4, 256, 0, stream>>>(hA, hB, x, fc1T, fc1b, fc2w, fc2b, out);
}

// Round 9
// 1160.399 us; speedup vs baseline: 5.0106x; 1.0487x over previous
//
#include <hip/hip_runtime.h>
#include <math.h>

// ---------------- problem constants ----------------
constexpr int BB     = 4;
constexpr int WINN   = 10;
constexpr int NNODES = 10000;
constexpr int NFEAT  = 8;
constexpr int NHID   = 64;
constexpr int NTOT   = BB * WINN * NNODES;   // 400000 stacked nodes
constexpr int NEDGE  = 3200000;
constexpr int NBN    = BB * NNODES;          // 40000 sequences
constexpr float EPSBN = 1e-5f;

#define DEVFN static __device__ __forceinline__

typedef float f4 __attribute__((ext_vector_type(4)));
typedef short s8v __attribute__((ext_vector_type(8)));
typedef unsigned short ushort_t;
typedef unsigned int uint_t;

DEVFN float sigmoidf_(float x) { return 1.0f / (1.0f + __expf(-x)); }
DEVFN float tanhf_(float x) { return 2.0f / (1.0f + __expf(-2.0f * x)) - 1.0f; }
DEVFN ushort_t f2bf(float f) {             // round-to-nearest-even bf16
    uint_t x = __float_as_uint(f);
    return (ushort_t)((x + 0x7FFFu + ((x >> 16) & 1u)) >> 16);
}
DEVFN float bf2f(ushort_t u) { return __uint_as_float(((uint_t)u) << 16); }

// ---------------- diagnostic ----------------
__global__ void k_diag(float* out, float wsz, int n) {
    int i = blockIdx.x * 256 + threadIdx.x;
    if (i < n) out[i] = wsz;
}

// ---------------- init: zero partitioned histogram + BN sums ----------------
__global__ void k_init(int* cntP, float* sums) {
    int i = blockIdx.x * 256 + threadIdx.x;   // grid covers 8*NTOT
    if (i < 8 * NTOT) cntP[i] = 0;
    if (i < 2048) sums[i] = 0.f;
}

// partition-local histogram: cntP[blockIdx%8][col]++  (lines stay XCD-local)
__global__ void k_hist(const int* __restrict__ ei, int* __restrict__ cntP) {
    int e = blockIdx.x * 256 + threadIdx.x;
    int p = blockIdx.x & 7;
    if (e < NEDGE) atomicAdd(&cntP[p * NTOT + ei[NEDGE + e]], 1);
}

// ---------------- exclusive scan of per-node totals (sum over 8 partitions) ----------------
__global__ void k_scan1(const int* __restrict__ cntP, int* __restrict__ ptr, int* __restrict__ tmp) {
    __shared__ int sdat[256];
    int tid = threadIdx.x;
    int base = blockIdx.x * 1024 + tid * 4;
    int v[4];
#pragma unroll
    for (int j = 0; j < 4; ++j) {
        int idx = base + j;
        int s = 0;
        if (idx < NTOT) {
#pragma unroll
            for (int p = 0; p < 8; ++p) s += cntP[p * NTOT + idx];
        }
        v[j] = s;
    }
    int sum = v[0] + v[1] + v[2] + v[3];
    sdat[tid] = sum;
    __syncthreads();
    for (int ofs = 1; ofs < 256; ofs <<= 1) {
        int x = (tid >= ofs) ? sdat[tid - ofs] : 0;
        __syncthreads();
        sdat[tid] += x;
        __syncthreads();
    }
    int run = sdat[tid] - sum;
    if (base + 0 < NTOT) ptr[base + 0] = run; run += v[0];
    if (base + 1 < NTOT) ptr[base + 1] = run; run += v[1];
    if (base + 2 < NTOT) ptr[base + 2] = run; run += v[2];
    if (base + 3 < NTOT) ptr[base + 3] = run;
    if (tid == 255) tmp[blockIdx.x] = sdat[255];
}

__global__ void k_scan2(int* tmp, int nb) {
    __shared__ int st[512];
    int tid = threadIdx.x;
    int v = (tid < nb) ? tmp[tid] : 0;
    st[tid] = v;
    __syncthreads();
    for (int ofs = 1; ofs < 512; ofs <<= 1) {
        int x = (tid >= ofs) ? st[tid - ofs] : 0;
        __syncthreads();
        st[tid] += x;
        __syncthreads();
    }
    if (tid < nb) tmp[tid] = st[tid] - v;
}

// finalize ptr; convert cntP in place to per-partition fill cursors cur8[p][node]
__global__ void k_scan3(int* __restrict__ ptr, int* __restrict__ cntP, const int* __restrict__ tmp) {
    int i = blockIdx.x * 256 + threadIdx.x;
    if (i < NTOT) {
        int p0 = ptr[i] + tmp[i >> 10];
        ptr[i] = p0;
        int run = p0;
#pragma unroll
        for (int p = 0; p < 8; ++p) {
            int c = cntP[p * NTOT + i];
            cntP[p * NTOT + i] = run;
            run += c;
        }
    }
    if (i == 0) ptr[NTOT] = NEDGE;
}

// CSR fill: epack[pos] = (row, ew), positions via partition-local cursor atomics
__global__ void k_fill(const int* __restrict__ ei, const float* __restrict__ ew,
                       int* __restrict__ cur8, int2* __restrict__ epack) {
    int e = blockIdx.x * 256 + threadIdx.x;
    if (e >= NEDGE) return;
    int p = blockIdx.x & 7;
    int row = ei[e], col = ei[NEDGE + e];
    int pos = atomicAdd(&cur8[p * NTOT + col], 1);
    epack[pos] = make_int2(row, __float_as_int(ew[e]));
}

// dinv[node] = rsqrt(1 + sum(ew over segment)) — coalesced, no atomics
__global__ void k_degcsr(const int* __restrict__ ptr, const int2* __restrict__ epack,
                         float* __restrict__ dinv) {
    int tid = threadIdx.x;
    int lane = tid & 63;
    int waveg = blockIdx.x * 4 + (tid >> 6);      // grid exact: NTOT/8 node-groups
    int g = lane >> 3, sub = lane & 7;
    int node = waveg * 8 + g;
    int beg = ptr[node], end = ptr[node + 1];
    float s = 0.f;
    for (int e = beg + sub; e < end; e += 8) s += __int_as_float(epack[e].y);
    s += __shfl_xor(s, 1, 64);
    s += __shfl_xor(s, 2, 64);
    s += __shfl_xor(s, 4, 64);
    if (sub == 0) dinv[node] = rsqrtf(1.0f + s);
}

// layer-1 gather over raw features (8 ch), norm computed inline
__global__ void k_gather8(const int* __restrict__ ptr, const int2* __restrict__ epack,
                          const float* __restrict__ x, const float* __restrict__ dinv,
                          float* __restrict__ aggX) {
    int tid = threadIdx.x;
    int lane = tid & 63;
    int waveg = blockIdx.x * 4 + (tid >> 6);
    int g = lane >> 3, ch = lane & 7;
    int node = waveg * 8 + g;
    int beg = ptr[node], end = ptr[node + 1];
    float dv = dinv[node];
    float accE = 0.f;
    int e = beg;
    for (; e + 1 < end; e += 2) {
        int2 p0 = epack[e], p1 = epack[e + 1];
        accE = fmaf(dinv[p0.x] * __int_as_float(p0.y), x[p0.x * 8 + ch], accE);
        accE = fmaf(dinv[p1.x] * __int_as_float(p1.y), x[p1.x * 8 + ch], accE);
    }
    if (e < end) {
        int2 p = epack[e];
        accE = fmaf(dinv[p.x] * __int_as_float(p.y), x[p.x * 8 + ch], accE);
    }
    aggX[node * 8 + ch] = dv * fmaf(dv, x[node * 8 + ch], accE);
}

// layer-2 gather (64 ch) from bf16 h1, norm inline, self-loop folded
__global__ void k_gather64(const int* __restrict__ ptr, const int2* __restrict__ epack,
                           const ushort_t* __restrict__ src, const float* __restrict__ dinv,
                           float* __restrict__ dst) {
    int lane = threadIdx.x & 63;
    int node = blockIdx.x * 4 + (threadIdx.x >> 6);
    int beg = ptr[node], end = ptr[node + 1];
    float dv = dinv[node];
    float accE = 0.f;
    int e = beg;
    for (; e + 1 < end; e += 2) {
        int2 p0 = epack[e], p1 = epack[e + 1];
        accE = fmaf(dinv[p0.x] * __int_as_float(p0.y), bf2f(src[(size_t)p0.x * 64 + lane]), accE);
        accE = fmaf(dinv[p1.x] * __int_as_float(p1.y), bf2f(src[(size_t)p1.x * 64 + lane]), accE);
    }
    if (e < end) {
        int2 p = epack[e];
        accE = fmaf(dinv[p.x] * __int_as_float(p.y), bf2f(src[(size_t)p.x * 64 + lane]), accE);
    }
    dst[(size_t)node * 64 + lane] = dv * fmaf(dv, bf2f(src[(size_t)node * 64 + lane]), accE);
}

// preH1 = relu(aggX @ W1 + b) + BN stats
__global__ void k_lin1(const float* __restrict__ aggX, const float* __restrict__ W,
                       const float* __restrict__ bias, float* __restrict__ h1,
                       float* __restrict__ sums) {
    __shared__ float sW[NFEAT * NHID];
    int tid = threadIdx.x;
    sW[tid] = W[tid];
    sW[tid + 256] = W[tid + 256];
    __syncthreads();
    int c = tid & 63;
    float b = bias[c];
    float s = 0.f, sq = 0.f;
    int stride = gridDim.x * 256;
    for (int i = blockIdx.x * 256 + tid; i < NTOT * 64; i += stride) {
        int n = i >> 6;
        float acc = b;
#pragma unroll
        for (int f = 0; f < NFEAT; ++f) acc = fmaf(aggX[n * NFEAT + f], sW[f * NHID + c], acc);
        acc = acc > 0.f ? acc : 0.f;
        h1[i] = acc;
        s += acc;
        sq = fmaf(acc, acc, sq);
    }
    __shared__ float ls[4][64], lq[4][64];
    int w = tid >> 6;
    ls[w][c] = s; lq[w][c] = sq;
    __syncthreads();
    if (tid < 64) {
        atomicAdd(&sums[tid], ls[0][tid] + ls[1][tid] + ls[2][tid] + ls[3][tid]);
        atomicAdd(&sums[64 + tid], lq[0][tid] + lq[1][tid] + lq[2][tid] + lq[3][tid]);
    }
}

__global__ void k_bn_final(const float* __restrict__ sums, const float* __restrict__ g,
                           const float* __restrict__ b, float* __restrict__ ss) {
    int i = threadIdx.x;
    if (i >= 64) return;
    float mean = sums[i] * (1.0f / NTOT);
    float var = sums[64 + i] * (1.0f / NTOT) - mean * mean;
    float sc = g[i] * rsqrtf(var + EPSBN);
    ss[i] = sc;
    ss[64 + i] = b[i] - mean * sc;
}

__global__ void k_bn_final8(const float* __restrict__ sums8, const float* __restrict__ g,
                            const float* __restrict__ b, float* __restrict__ ss) {
    int i = threadIdx.x;
    if (i >= 64) return;
    float S = 0.f, Q = 0.f;
#pragma unroll
    for (int m = 0; m < 8; ++m) { S += sums8[m * 128 + i]; Q += sums8[m * 128 + 64 + i]; }
    float mean = S * (1.0f / NTOT);
    float var = Q * (1.0f / NTOT) - mean * mean;
    float sc = g[i] * rsqrtf(var + EPSBN);
    ss[i] = sc;
    ss[64 + i] = b[i] - mean * sc;
}

// h1bf = bf16(preH1*sc + sh)   (BN1 apply + cast)
__global__ void k_bn1cast(const float* __restrict__ pre, const float* __restrict__ ss,
                          ushort_t* __restrict__ dst) {
    int c = threadIdx.x & 63;
    float sc = ss[c], sh = ss[64 + c];
    int stride = gridDim.x * 256;
    for (int i = blockIdx.x * 256 + threadIdx.x; i < NTOT * 64; i += stride)
        dst[i] = f2bf(fmaf(pre[i], sc, sh));
}

// h2bf = bf16(relu(row @ W2 + b)) + BN stats (pre-BN; BN2 folded into LSTM weights)
__global__ void k_lin2b(const float* __restrict__ io, const float* __restrict__ W2,
                        const float* __restrict__ bias, ushort_t* __restrict__ dst,
                        float* __restrict__ sums8) {
    __shared__ __align__(16) float srow[4][64];
    __shared__ float ls[4][64], lq[4][64];
    int lane = threadIdx.x & 63, wv = threadIdx.x >> 6;
    float wc[64];
#pragma unroll
    for (int h = 0; h < 64; ++h) wc[h] = W2[h * 64 + lane];
    float b = bias[lane];
    float s = 0.f, sq = 0.f;
    int wid = blockIdx.x * 4 + wv;
    int nw = gridDim.x * 4;
    for (int row = wid; row < NTOT; row += nw) {
        const float* hr = io + (size_t)row * 64;
        srow[wv][lane] = hr[lane];
        float acc = b;
#pragma unroll
        for (int h4 = 0; h4 < 16; ++h4) {
            float4 iv = *reinterpret_cast<const float4*>(&srow[wv][h4 * 4]);
            acc = fmaf(iv.x, wc[h4 * 4 + 0], acc);
            acc = fmaf(iv.y, wc[h4 * 4 + 1], acc);
            acc = fmaf(iv.z, wc[h4 * 4 + 2], acc);
            acc = fmaf(iv.w, wc[h4 * 4 + 3], acc);
        }
        acc = acc > 0.f ? acc : 0.f;
        dst[(size_t)row * 64 + lane] = f2bf(acc);
        s += acc;
        sq = fmaf(acc, acc, sq);
    }
    ls[wv][lane] = s; lq[wv][lane] = sq;
    __syncthreads();
    if (threadIdx.x < 64) {
        float S = ls[0][lane] + ls[1][lane] + ls[2][lane] + ls[3][lane];
        float Q = lq[0][lane] + lq[1][lane] + lq[2][lane] + lq[3][lane];
        float* d = sums8 + (blockIdx.x & 7) * 128;
        atomicAdd(&d[lane], S);
        atomicAdd(&d[64 + lane], Q);
    }
}

// build MFMA-layout weights: wB1f fp32 [256][192]; wB2h bf16 [256][128]; biases; fc1T
__global__ void k_prep(const float* __restrict__ wih1, const float* __restrict__ whh1,
                       const float* __restrict__ bih1, const float* __restrict__ bhh1,
                       const float* __restrict__ wih2, const float* __restrict__ whh2,
                       const float* __restrict__ bih2, const float* __restrict__ bhh2,
                       const float* __restrict__ fc1w,
                       float* wB1f, float* b1, ushort_t* wB2h, float* b2, float* fc1T) {
    int i = blockIdx.x * 256 + threadIdx.x;
    if (i < 256 * 192) {
        int n = i / 192, k = i - n * 192;
        wB1f[i] = (k < 128) ? wih1[n * 128 + k] : whh1[n * 64 + (k - 128)];
    }
    if (i < 256 * 128) {
        int n = i >> 7, k = i & 127;
        wB2h[i] = f2bf((k < 64) ? wih2[n * 64 + k] : whh2[n * 64 + (k - 64)]);
    }
    if (i < 208 * 64) {
        int k = i >> 6, o = i & 63;
        fc1T[i] = fc1w[o * 208 + k];
    }
    if (i < 256) { b1[i] = bih1[i] + bhh1[i]; b2[i] = bih2[i] + bhh2[i]; }
}

// fold BN2 affine into wB1f cols 64..127 + b1, then convert wB1f -> bf16
__global__ void k_fold2(float* __restrict__ wB1f, float* __restrict__ b1,
                        const float* __restrict__ ss2, ushort_t* __restrict__ wB1h) {
    int n = threadIdx.x;   // 256
    float acc = 0.f;
#pragma unroll
    for (int m = 0; m < 64; ++m) {
        float w = wB1f[n * 192 + 64 + m];
        acc = fmaf(w, ss2[64 + m], acc);
        wB1f[n * 192 + 64 + m] = w * ss2[m];
    }
    b1[n] += acc;
    __syncthreads();
    for (int j = n; j < 256 * 192; j += 256) wB1h[j] = f2bf(wB1f[j]);
}

// ---------------- MFMA 2-layer LSTM: 4 waves/block, 16 rows, weights in registers ----
__global__ __launch_bounds__(256, 2) void k_lstm_mfma4(
    const ushort_t* __restrict__ h1bf, const ushort_t* __restrict__ h2bf,
    const ushort_t* __restrict__ wB1, const ushort_t* __restrict__ wB2,
    const float* __restrict__ bs1, const float* __restrict__ bs2,
    float* __restrict__ hA, float* __restrict__ hB) {
    __shared__ ushort_t hx1[1024], hx2[1024];   // [16 rows][64 units], 16B-granule XOR swizzle
    int tid = threadIdx.x;
    int lane = tid & 63, wv = tid >> 6;
    int c15 = lane & 15, g4 = lane >> 4;
    int g8 = g4 * 8;
    int bn0 = blockIdx.x * 16;
    int b = bn0 / NNODES, nn0 = bn0 - b * NNODES;

    for (int i = tid; i < 512; i += 256) { ((uint_t*)hx1)[i] = 0u; ((uint_t*)hx2)[i] = 0u; }

    s8v w1f[4][6], w2f[4][4];
#pragma unroll
    for (int j = 0; j < 4; ++j) {
        const ushort_t* base1 = wB1 + (size_t)((wv + 4 * j) * 16 + c15) * 192 + g8;
#pragma unroll
        for (int kk = 0; kk < 6; ++kk) w1f[j][kk] = *(const s8v*)(base1 + kk * 32);
        const ushort_t* base2 = wB2 + (size_t)((wv + 4 * j) * 16 + c15) * 128 + g8;
#pragma unroll
        for (int kk = 0; kk < 4; ++kk) w2f[j][kk] = *(const s8v*)(base2 + kk * 32);
    }
    float bi1[4], bi2[4];
#pragma unroll
    for (int j = 0; j < 4; ++j) {
        bi1[j] = bs1[(wv + 4 * j) * 16 + c15];
        bi2[j] = bs2[(wv + 4 * j) * 16 + c15];
    }
    float cA[4], cB[4];
#pragma unroll
    for (int q = 0; q < 4; ++q) { cA[q] = 0.f; cB[q] = 0.f; }

    int r7 = c15 & 7;
    int a_lo = c15 * 64 + ((g4 ^ r7) << 3);
    int a_hi = c15 * 64 + (((4 + g4) ^ r7) << 3);
    int u = wv * 16 + c15;
    int hxcol_hi = (u >> 3) << 3;
    int u7 = u & 7;

    __syncthreads();

    for (int t = 0; t < WINN; ++t) {
        size_t node = (size_t)((b * WINN + t) * NNODES + nn0 + c15) * 64 + g8;
        s8v a[6];
        a[0] = *(const s8v*)(h1bf + node);
        a[1] = *(const s8v*)(h1bf + node + 32);
        a[2] = *(const s8v*)(h2bf + node);
        a[3] = *(const s8v*)(h2bf + node + 32);
        a[4] = *(const s8v*)(&hx1[a_lo]);
        a[5] = *(const s8v*)(&hx1[a_hi]);

        f4 acc[4];
#pragma unroll
        for (int j = 0; j < 4; ++j) { f4 v = {bi1[j], bi1[j], bi1[j], bi1[j]}; acc[j] = v; }
#pragma unroll
        for (int j = 0; j < 4; ++j)
#pragma unroll
            for (int kk = 0; kk < 6; ++kk)
                acc[j] = __builtin_amdgcn_mfma_f32_16x16x32_bf16(a[kk], w1f[j][kk], acc[j], 0, 0, 0);
        __syncthreads();
#pragma unroll
        for (int q = 0; q < 4; ++q) {
            float ig = sigmoidf_(acc[0][q]);
            float fg = sigmoidf_(acc[1][q]);
            float gg = tanhf_(acc[2][q]);
            float og = sigmoidf_(acc[3][q]);
            float cv = fmaf(fg, cA[q], ig * gg);
            cA[q] = cv;
            float hv = og * tanhf_(cv);
            int rr = g4 * 4 + q;
            hx1[rr * 64 + (hxcol_hi ^ ((rr & 7) << 3)) + u7] = f2bf(hv);
        }
        __syncthreads();

        s8v r[4];
        r[0] = *(const s8v*)(&hx1[a_lo]);
        r[1] = *(const s8v*)(&hx1[a_hi]);
        r[2] = *(const s8v*)(&hx2[a_lo]);
        r[3] = *(const s8v*)(&hx2[a_hi]);
#pragma unroll
        for (int j = 0; j < 4; ++j) { f4 v = {bi2[j], bi2[j], bi2[j], bi2[j]}; acc[j] = v; }
#pragma unroll
        for (int j = 0; j < 4; ++j)
#pragma unroll
            for (int kk = 0; kk < 4; ++kk)
                acc[j] = __builtin_amdgcn_mfma_f32_16x16x32_bf16(r[kk], w2f[j][kk], acc[j], 0, 0, 0);
        __syncthreads();
#pragma unroll
        for (int q = 0; q < 4; ++q) {
            float ig = sigmoidf_(acc[0][q]);
            float fg = sigmoidf_(acc[1][q]);
            float gg = tanhf_(acc[2][q]);
            float og = sigmoidf_(acc[3][q]);
            float cv = fmaf(fg, cB[q], ig * gg);
            cB[q] = cv;
            float hv = og * tanhf_(cv);
            int rr = g4 * 4 + q;
            hx2[rr * 64 + (hxcol_hi ^ ((rr & 7) << 3)) + u7] = f2bf(hv);
        }
        __syncthreads();
    }
    for (int i = tid; i < 1024; i += 256) {
        int rr = i >> 6, uu = i & 63;
        int hw = rr * 64 + ((((uu >> 3) ^ (rr & 7)) << 3)) + (uu & 7);
        hA[(size_t)(bn0 + rr) * 64 + uu] = bf2f(hx1[hw]);
        hB[(size_t)(bn0 + rr) * 64 + uu] = bf2f(hx2[hw]);
    }
}

// head: z = relu([hn1|hn2|skip] @ fc1^T + b1); out = relu(z @ fc2^T + b2)
__global__ void k_head(const float* __restrict__ hA, const float* __restrict__ hB,
                       const float* __restrict__ x, const float* __restrict__ fc1T,
                       const float* __restrict__ fc1b, const float* __restrict__ fc2w,
                       const float* __restrict__ fc2b, float* __restrict__ out) {
    int lane = threadIdx.x & 63, wv = threadIdx.x >> 6;
    int bn = blockIdx.x * 4 + wv;
    __shared__ float sz[4][208];
    int b = bn / NNODES, nn = bn - b * NNODES;
    for (int k = lane; k < 208; k += 64) {
        float v;
        if (k < 64) v = hA[(size_t)bn * 64 + k];
        else if (k < 128) v = hB[(size_t)bn * 64 + (k - 64)];
        else {
            int kk = k - 128;
            int w = kk >> 3, f = kk & 7;
            v = x[(size_t)((b * WINN + w) * NNODES + nn) * NFEAT + f];
        }
        sz[wv][k] = v;
    }
    __syncthreads();
    float acc = fc1b[lane];
    for (int k = 0; k < 208; ++k) acc = fmaf(sz[wv][k], fc1T[k * 64 + lane], acc);
    acc = acc > 0.f ? acc : 0.f;
    float v = acc * fc2w[lane];
#pragma unroll
    for (int m = 32; m >= 1; m >>= 1) v += __shfl_xor(v, m, 64);
    if (lane == 0) {
        float z = v + fc2b[0];
        out[bn] = z > 0.f ? z : 0.f;
    }
}

// ---------------- launch ----------------
extern "C" void kernel_launch(void* const* d_in, const int* in_sizes, int n_in,
                              void* d_out, int out_size, void* d_ws, size_t ws_size,
                              hipStream_t stream) {
    const float* x     = (const float*)d_in[0];
    const int*   ei    = (const int*)d_in[1];
    const float* ew    = (const float*)d_in[2];
    const float* c1w   = (const float*)d_in[3];
    const float* c1b   = (const float*)d_in[4];
    const float* c2w   = (const float*)d_in[5];
    const float* c2b   = (const float*)d_in[6];
    const float* bn1g  = (const float*)d_in[7];
    const float* bn1b  = (const float*)d_in[8];
    const float* bn2g  = (const float*)d_in[9];
    const float* bn2b  = (const float*)d_in[10];
    const float* wih1  = (const float*)d_in[11];
    const float* whh1  = (const float*)d_in[12];
    const float* bih1  = (const float*)d_in[13];
    const float* bhh1  = (const float*)d_in[14];
    const float* wih2  = (const float*)d_in[15];
    const float* whh2  = (const float*)d_in[16];
    const float* bih2  = (const float*)d_in[17];
    const float* bhh2  = (const float*)d_in[18];
    const float* fc1w  = (const float*)d_in[19];
    const float* fc1b  = (const float*)d_in[20];
    const float* fc2w  = (const float*)d_in[21];
    const float* fc2b  = (const float*)d_in[22];
    float* out = (float*)d_out;

    float* ws = (float*)d_ws;
    size_t off = 0;
    auto A = [&](size_t n) { float* p = ws + off; off += n; return p; };
    float* dinv   = A(NTOT);
    float* aggX   = A((size_t)NTOT * NFEAT);
    float* big    = A((size_t)NTOT * 64);       // preH1 (layer1), then agg2 (layer2)
    ushort_t* h1bf = (ushort_t*)A((size_t)NTOT * 32);   // NTOT*64 bf16
    ushort_t* h2bf = (ushort_t*)A((size_t)NTOT * 32);

    // union: CSR (GCN phase) aliases final LSTM states (LSTM/head phase)
    // CSR = epack(2*NEDGE) + ptr(NTOT+1) + cntP/cur8(8*NTOT) = 10,000,001 ints
    size_t uoff = off;
    float* hA = A((size_t)NBN * 64);            // 2.56M
    float* hB = A((size_t)NBN * 64);            // 2.56M
    A(2 * (size_t)NEDGE + (NTOT + 1) + 8 * (size_t)NTOT - 2 * (size_t)NBN * 64);
    int2* epack = (int2*)(ws + uoff);
    int*  ptr   = (int*)(epack + NEDGE);        // NTOT+1
    int*  cntP  = ptr + NTOT + 1;               // 8*NTOT (hist, then cursors)

    float* wB1f = A(256 * 192);
    ushort_t* wB1h = (ushort_t*)A(256 * 96);
    ushort_t* wB2h = (ushort_t*)A(256 * 64);
    float* b1   = A(256);
    float* b2   = A(256);
    float* fc1T = A(208 * 64);
    float* sums = A(2048);
    float* ss1  = A(128);
    float* ss2  = A(128);
    float* scanTmpF = A(512);
    int* scanTmp = (int*)scanTmpF;
    // total ~64.9M floats = 259.6 MB < 256 MiB (268.4 MB)

    if (ws_size < off * sizeof(float)) {
        k_diag<<<(out_size + 255) / 256, 256, 0, stream>>>(out, (float)ws_size, out_size);
        return;
    }

    constexpr int SCAN_NB = (NTOT + 1023) / 1024;

    // CSR build: partitioned hist -> scan -> fill -> degree-from-CSR
    k_init<<<8 * NTOT / 256, 256, 0, stream>>>(cntP, sums);
    k_hist<<<NEDGE / 256, 256, 0, stream>>>(ei, cntP);
    k_scan1<<<SCAN_NB, 256, 0, stream>>>(cntP, ptr, scanTmp);
    k_scan2<<<1, 512, 0, stream>>>(scanTmp, SCAN_NB);
    k_scan3<<<(NTOT + 255) / 256, 256, 0, stream>>>(ptr, cntP, scanTmp);
    k_fill<<<NEDGE / 256, 256, 0, stream>>>(ei, ew, cntP, epack);
    k_degcsr<<<NTOT / 8 / 4, 256, 0, stream>>>(ptr, epack, dinv);
    k_prep<<<192, 256, 0, stream>>>(wih1, whh1, bih1, bhh1, wih2, whh2, bih2, bhh2,
                                    fc1w, wB1f, b1, wB2h, b2, fc1T);

    // ---- GCN layer 1 ----
    k_gather8<<<NTOT / 8 / 4, 256, 0, stream>>>(ptr, epack, x, dinv, aggX);
    k_lin1<<<512, 256, 0, stream>>>(aggX, c1w, c1b, big, sums);
    k_bn_final<<<1, 64, 0, stream>>>(sums, bn1g, bn1b, ss1);
    k_bn1cast<<<2048, 256, 0, stream>>>(big, ss1, h1bf);

    // ---- GCN layer 2 ----
    k_gather64<<<NTOT / 4, 256, 0, stream>>>(ptr, epack, h1bf, dinv, big);
    k_lin2b<<<2048, 256, 0, stream>>>(big, c2w, c2b, h2bf, sums + 128);
    k_bn_final8<<<1, 64, 0, stream>>>(sums + 128, bn2g, bn2b, ss2);
    k_fold2<<<1, 256, 0, stream>>>(wB1f, b1, ss2, wB1h);

    // ---- MFMA LSTM: weights resident in VGPRs ----
    k_lstm_mfma4<<<NBN / 16, 256, 0, stream>>>(h1bf, h2bf, wB1h, wB2h, b1, b2, hA, hB);

    // ---- head ----
    k_head<<<NBN / 4, 256, 0, stream>>>(hA, hB, x, fc1T, fc1b, fc2w, fc2b, out);
}